// Round 9
// baseline (820.057 us; speedup 1.0000x reference)
//
#include <hip/hip_runtime.h>
#include <hip/hip_cooperative_groups.h>
#include <math.h>

namespace cg = cooperative_groups;

#define N_NODES 20000
#define N_EDGES 200000
#define DM 128
#define NH 8

typedef __attribute__((ext_vector_type(8))) short bf16x8;
typedef __attribute__((ext_vector_type(4))) float f32x4;

__device__ __forceinline__ unsigned short f2b(float f) {
  unsigned int u = __float_as_uint(f);
  unsigned int r = (u + 0x7FFFu + ((u >> 16) & 1u)) >> 16;  // RNE
  return (unsigned short)r;
}
__device__ __forceinline__ float b2f(unsigned short s) {
  return __uint_as_float(((unsigned int)s) << 16);
}

struct P {
  const float* x;
  const int* srcE;
  const int* dstE;
  const float* Ws;
  const float* als;
  const float* ars;
  const float* bs;
  const float* W_last;
  const float* al_last;
  const float* ar_last;
  const float* b_last;
  float* out;
  float* h;
  float* elr;
  float* mb;
  unsigned short* hb;
  unsigned short* feat;
  unsigned short* g;
  unsigned short* wsz;
  unsigned short* wpsz;
  unsigned short* wlrsz;
  int* deg;
  int* off;
  int* cursor;
  int* csr_src;
};

// ---------------- device bodies ----------------
template <int K, bool LAST>
__device__ __forceinline__ void dev_gemm(int tile, const unsigned short* __restrict__ A,
                                         const unsigned short* __restrict__ Bsz,
                                         const float* __restrict__ hres,
                                         const float* __restrict__ mbv,
                                         unsigned short* __restrict__ Cb,
                                         float* __restrict__ Cf,
                                         const float* __restrict__ al,
                                         const float* __restrict__ ar,
                                         float* __restrict__ elr, int lane, int wid) {
  const int wrow = wid & 1, wc = wid >> 1;
  const int r0 = tile * 32;
  const int arow = r0 + wrow * 16 + (lane & 15);
  const int kg = lane >> 4;

  f32x4 acc[4];
#pragma unroll
  for (int fi = 0; fi < 4; ++fi) acc[fi] = {0.f, 0.f, 0.f, 0.f};

  const bf16x8* Ap = (const bf16x8*)(A + (size_t)arow * K + kg * 8);
#pragma unroll 4
  for (int ks = 0; ks < K / 32; ++ks) {
    bf16x8 a = Ap[ks * 4];
#pragma unroll
    for (int fi = 0; fi < 4; ++fi) {
      int f = wc * 4 + fi;
      bf16x8 b = *(const bf16x8*)(Bsz + (((size_t)(ks * 8 + f) * 64 + lane) << 3));
      acc[fi] = __builtin_amdgcn_mfma_f32_16x16x32_bf16(a, b, acc[fi], 0, 0, 0);
    }
  }

  const int rbase = r0 + wrow * 16 + (lane >> 4) * 4;
#pragma unroll
  for (int fi = 0; fi < 4; ++fi) {
    int col = wc * 64 + fi * 16 + (lane & 15);
#pragma unroll
    for (int r = 0; r < 4; ++r) {
      int row = rbase + r;
      float v = acc[fi][r];
      if (LAST)
        Cf[(size_t)row * DM + col] = v + hres[(size_t)row * DM + col] + mbv[col];
      else
        Cb[(size_t)row * DM + col] = f2b(v);
    }
  }

  if (!LAST) {
#pragma unroll
    for (int fi = 0; fi < 4; ++fi) {
      int hh = wc * 4 + fi;
      float alv = al[hh * 16 + (lane & 15)];
      float arv = ar[hh * 16 + (lane & 15)];
#pragma unroll
      for (int r = 0; r < 4; ++r) {
        float pl = acc[fi][r] * alv;
        float pr = acc[fi][r] * arv;
#pragma unroll
        for (int msk = 1; msk < 16; msk <<= 1) {
          pl += __shfl_xor(pl, msk, 64);
          pr += __shfl_xor(pr, msk, 64);
        }
        if ((lane & 15) == 0) {
          int row = rbase + r;
          elr[row * 16 + hh] = pl;
          elr[row * 16 + 8 + hh] = pr;
        }
      }
    }
  }
}

__device__ __forceinline__ void dev_elr_last(int tile, const unsigned short* __restrict__ hb,
                                             const unsigned short* __restrict__ wlrsz,
                                             float* __restrict__ elr, int lane, int wid) {
  const int r0 = tile * 64 + wid * 16;
  const int arow = r0 + (lane & 15);
  const int kg = lane >> 4;
  f32x4 acc = {0.f, 0.f, 0.f, 0.f};
  int arowc = arow < N_NODES ? arow : N_NODES - 1;
  const bf16x8* Ap = (const bf16x8*)(hb + (size_t)arowc * 128 + kg * 8);
#pragma unroll
  for (int ks = 0; ks < 4; ++ks) {
    bf16x8 a = Ap[ks * 4];
    bf16x8 b = *(const bf16x8*)(wlrsz + (((size_t)ks * 64 + lane) << 3));
    acc = __builtin_amdgcn_mfma_f32_16x16x32_bf16(a, b, acc, 0, 0, 0);
  }
  const int col = lane & 15;
  const int rbase = r0 + (lane >> 4) * 4;
#pragma unroll
  for (int r = 0; r < 4; ++r) {
    int row = rbase + r;
    if (row < N_NODES) elr[row * 16 + col] = acc[r];
  }
}

__device__ __forceinline__ void dev_fused_small(int t, const int* __restrict__ off,
                                                const int* __restrict__ csr_src,
                                                const unsigned short* __restrict__ feat,
                                                const float* __restrict__ elr,
                                                const float* __restrict__ bias,
                                                float* __restrict__ h,
                                                unsigned short* __restrict__ hb, int lane,
                                                int wid, float (*a_lds)[64], int (*s_lds)[8],
                                                float (*zi_lds)[8]) {
  const int e_loc = lane >> 3, hh = lane & 7;
  const int hg = lane >> 3;
  const int beg = off[t], end = off[t + 1];
  const float ert = elr[t * 16 + 8 + hh];

  int e = beg + e_loc;
  bool val = e < end;
  int s = val ? csr_src[e] : 0;
  float xl = val ? elr[s * 16 + hh] : 0.f;

  float z = 0.f, acc0 = 0.f, acc1 = 0.f;
  for (int base = beg; base < end; base += 8) {
    float ex = 0.f;
    if (val) {
      float xv = xl + ert;
      xv = xv > 0.f ? xv : 0.2f * xv;
      ex = __expf(xv);
    }
    a_lds[wid][lane] = ex;
    if (hh == 0) s_lds[wid][e_loc] = s;
    __builtin_amdgcn_wave_barrier();
    asm volatile("s_waitcnt lgkmcnt(0)" ::: "memory");
    z += ex;
    int en = base + 8 + e_loc;
    bool valn = en < end;
    int sn = valn ? csr_src[en] : 0;
    float xln = valn ? elr[sn * 16 + hh] : 0.f;
    int n = min(8, end - base);
    for (int e2 = 0; e2 < n; ++e2) {
      int s2 = s_lds[wid][e2];
      float a = a_lds[wid][e2 * 8 + hg];
      unsigned int hv = *(const unsigned int*)&feat[(size_t)s2 * 128 + 2 * lane];
      acc0 += a * b2f((unsigned short)(hv & 0xffffu));
      acc1 += a * b2f((unsigned short)(hv >> 16));
    }
    __builtin_amdgcn_wave_barrier();
    s = sn;
    xl = xln;
    val = valn;
  }
  z += __shfl_xor(z, 8, 64);
  z += __shfl_xor(z, 16, 64);
  z += __shfl_xor(z, 32, 64);
  if (e_loc == 0) zi_lds[wid][hh] = (z > 0.f) ? 1.f / z : 0.f;
  __builtin_amdgcn_wave_barrier();
  asm volatile("s_waitcnt lgkmcnt(0)" ::: "memory");
  float zi = zi_lds[wid][hg];

  float2 bv = *(const float2*)&bias[2 * lane];
  float v0 = acc0 * zi + bv.x;
  float v1 = acc1 * zi + bv.y;
  v0 = v0 > 0.f ? v0 : expm1f(v0);
  v1 = v1 > 0.f ? v1 : expm1f(v1);
  size_t idx = (size_t)t * 128 + 2 * lane;
  float2 hv = *(const float2*)&h[idx];
  float nh0 = hv.x + v0;
  float nh1 = hv.y + v1;
  *(float2*)&h[idx] = make_float2(nh0, nh1);
  *(ushort2*)&hb[idx] = make_ushort2(f2b(nh0), f2b(nh1));
}

__device__ __forceinline__ void dev_fused_last(int t, const int* __restrict__ off,
                                               const int* __restrict__ csr_src,
                                               const unsigned short* __restrict__ hb,
                                               const float* __restrict__ elr,
                                               unsigned short* __restrict__ g, int lane,
                                               int wid, float (*a_lds)[64], int (*s_lds)[8],
                                               float (*zi_lds)[8]) {
  const int e_loc = lane >> 3, hh = lane & 7;
  const int beg = off[t], end = off[t + 1];
  const float ert = elr[t * 16 + 8 + hh];

  int e = beg + e_loc;
  bool val = e < end;
  int s = val ? csr_src[e] : 0;
  float xl = val ? elr[s * 16 + hh] : 0.f;

  float z = 0.f;
  float accA[8], accB[8];
#pragma unroll
  for (int k = 0; k < 8; ++k) accA[k] = accB[k] = 0.f;

  for (int base = beg; base < end; base += 8) {
    float ex = 0.f;
    if (val) {
      float xv = xl + ert;
      xv = xv > 0.f ? xv : 0.2f * xv;
      ex = __expf(xv);
    }
    a_lds[wid][lane] = ex;
    if (hh == 0) s_lds[wid][e_loc] = s;
    __builtin_amdgcn_wave_barrier();
    asm volatile("s_waitcnt lgkmcnt(0)" ::: "memory");
    z += ex;
    int en = base + 8 + e_loc;
    bool valn = en < end;
    int sn = valn ? csr_src[en] : 0;
    float xln = valn ? elr[sn * 16 + hh] : 0.f;
    int n = min(8, end - base);
    for (int e2 = 0; e2 < n; ++e2) {
      int s2 = s_lds[wid][e2];
      float4 pa = *(const float4*)&a_lds[wid][e2 * 8];
      float4 pb = *(const float4*)&a_lds[wid][e2 * 8 + 4];
      unsigned int hv = *(const unsigned int*)&hb[(size_t)s2 * 128 + 2 * lane];
      float h0 = b2f((unsigned short)(hv & 0xffffu));
      float h1 = b2f((unsigned short)(hv >> 16));
      accA[0] += pa.x * h0; accB[0] += pa.x * h1;
      accA[1] += pa.y * h0; accB[1] += pa.y * h1;
      accA[2] += pa.z * h0; accB[2] += pa.z * h1;
      accA[3] += pa.w * h0; accB[3] += pa.w * h1;
      accA[4] += pb.x * h0; accB[4] += pb.x * h1;
      accA[5] += pb.y * h0; accB[5] += pb.y * h1;
      accA[6] += pb.z * h0; accB[6] += pb.z * h1;
      accA[7] += pb.w * h0; accB[7] += pb.w * h1;
    }
    __builtin_amdgcn_wave_barrier();
    s = sn;
    xl = xln;
    val = valn;
  }
  z += __shfl_xor(z, 8, 64);
  z += __shfl_xor(z, 16, 64);
  z += __shfl_xor(z, 32, 64);
  if (e_loc == 0) zi_lds[wid][hh] = (z > 0.f) ? 1.f / z : 0.f;
  __builtin_amdgcn_wave_barrier();
  asm volatile("s_waitcnt lgkmcnt(0)" ::: "memory");
  float4 zia = *(const float4*)&zi_lds[wid][0];
  float4 zib = *(const float4*)&zi_lds[wid][4];
  float ziv[8] = {zia.x, zia.y, zia.z, zia.w, zib.x, zib.y, zib.z, zib.w};
#pragma unroll
  for (int h2 = 0; h2 < 8; ++h2) {
    *(ushort2*)&g[(size_t)t * 1024 + h2 * 128 + 2 * lane] =
        make_ushort2(f2b(accA[h2] * ziv[h2]), f2b(accB[h2] * ziv[h2]));
  }
}

// ---------------- the cooperative mega-kernel ----------------
__global__ __launch_bounds__(256, 4) void mega(P p) {
  cg::grid_group grid = cg::this_grid();
  __shared__ float a_lds[4][64];
  __shared__ int s_lds[4][8];
  __shared__ float zi_lds[4][8];
  __shared__ int scan_lds[256];

  const int tid = threadIdx.x;
  const int lane = tid & 63, wid = tid >> 6;
  const int bid = blockIdx.x, nb = gridDim.x;
  const int gtid = bid * 256 + tid;
  const int GSZ = nb * 256;

  // ---- phase A: deg zero + weight prep ----
  for (int i = gtid; i < N_NODES; i += GSZ) p.deg[i] = 0;
  for (int i = gtid; i < 2 * 16384; i += GSZ) {  // layers 0/1 B swizzle
    int layer = i >> 14;
    int r = i & 16383;
    int j = r & 7, l = (r >> 3) & 63, f = (r >> 9) & 7, ks = r >> 12;
    int k = ks * 32 + ((l >> 4) << 3) + j;
    int n = f * 16 + (l & 15);
    p.wsz[i] = f2b(p.Ws[(size_t)layer * 16384 + k * 128 + n]);
  }
  for (int i = gtid; i < 131072; i += GSZ) {  // last-layer B swizzle (1/8 mean folded)
    int j = i & 7, l = (i >> 3) & 63, f = (i >> 9) & 7, ks = i >> 12;
    int k = ks * 32 + ((l >> 4) << 3) + j;
    int n = f * 16 + (l & 15);
    int h_ = k >> 7, ko = k & 127;
    p.wpsz[i] = f2b(p.W_last[(size_t)ko * 1024 + h_ * 128 + n] * 0.125f);
  }
  for (int i = gtid; i < 2048; i += GSZ) {  // wlr fragment build
    int j = i & 7, l = (i >> 3) & 63, ks = i >> 9;
    int k = ks * 32 + ((l >> 4) << 3) + j;
    int n = l & 15;
    int hh = n & 7;
    const float* av = (n < 8) ? (p.al_last + hh * 128) : (p.ar_last + hh * 128);
    float s = 0.f;
    for (int d = 0; d < 128; ++d) s += p.W_last[(size_t)k * 1024 + hh * 128 + d] * av[d];
    p.wlrsz[i] = f2b(s);
  }
  for (int i = gtid; i < 128; i += GSZ) {
    float s = 0.f;
#pragma unroll
    for (int hh = 0; hh < 8; ++hh) s += p.b_last[hh * 128 + i];
    p.mb[i] = s * 0.125f;
  }
  grid.sync();

  // ---- phase B: cast x (float4) + deg count ----
  for (int i = gtid; i < (N_NODES * DM) / 4; i += GSZ) {
    float4 v = ((const float4*)p.x)[i];
    ((float4*)p.h)[i] = v;
    ((ushort4*)p.hb)[i] = make_ushort4(f2b(v.x), f2b(v.y), f2b(v.z), f2b(v.w));
  }
  for (int e = gtid; e < N_EDGES; e += GSZ) atomicAdd(&p.deg[p.dstE[e]], 1);
  grid.sync();

  // ---- phase C: gemm layer0 (blocks 0..nb-2)  ||  CSR scan (block nb-1) ----
  if (bid == nb - 1) {
    const int NPT = (N_NODES + 255) / 256;  // 79
    int b0 = tid * NPT;
    int b1 = min(N_NODES, b0 + NPT);
    int ssum = 0;
    for (int j = b0; j < b1; ++j) ssum += p.deg[j];
    scan_lds[tid] = ssum;
    __syncthreads();
    for (int ofs = 1; ofs < 256; ofs <<= 1) {
      int v = (tid >= ofs) ? scan_lds[tid - ofs] : 0;
      __syncthreads();
      scan_lds[tid] += v;
      __syncthreads();
    }
    int run = (tid > 0) ? scan_lds[tid - 1] : 0;
    for (int j = b0; j < b1; ++j) {
      p.off[j] = run;
      p.cursor[j] = run;
      run += p.deg[j];
    }
    if (tid == 255) p.off[N_NODES] = scan_lds[255];
  } else {
    for (int t = bid; t < N_NODES / 32; t += nb - 1)
      dev_gemm<DM, false>(t, p.hb, p.wsz, nullptr, nullptr, p.feat, nullptr, p.als, p.ars,
                          p.elr, lane, wid);
  }
  grid.sync();

  // ---- phase D: scatter ----
  for (int e = gtid; e < N_EDGES; e += GSZ) {
    int pos = atomicAdd(&p.cursor[p.dstE[e]], 1);
    p.csr_src[pos] = p.srcE[e];
  }
  grid.sync();

  // ---- phase E: fused layer0 ----
  for (int tb = bid; tb < N_NODES / 4; tb += nb)
    dev_fused_small(tb * 4 + wid, p.off, p.csr_src, p.feat, p.elr, p.bs, p.h, p.hb, lane,
                    wid, a_lds, s_lds, zi_lds);
  grid.sync();

  // ---- phase F: gemm layer1 ----
  for (int t = bid; t < N_NODES / 32; t += nb)
    dev_gemm<DM, false>(t, p.hb, p.wsz + 16384, nullptr, nullptr, p.feat, nullptr,
                        p.als + 128, p.ars + 128, p.elr, lane, wid);
  grid.sync();

  // ---- phase G: fused layer1 ----
  for (int tb = bid; tb < N_NODES / 4; tb += nb)
    dev_fused_small(tb * 4 + wid, p.off, p.csr_src, p.feat, p.elr, p.bs + 128, p.h, p.hb,
                    lane, wid, a_lds, s_lds, zi_lds);
  grid.sync();

  // ---- phase H: elr_last ----
  for (int t = bid; t < (N_NODES + 63) / 64; t += nb)
    dev_elr_last(t, p.hb, p.wlrsz, p.elr, lane, wid);
  grid.sync();

  // ---- phase I: fused_last ----
  for (int tb = bid; tb < N_NODES / 4; tb += nb)
    dev_fused_last(tb * 4 + wid, p.off, p.csr_src, p.hb, p.elr, p.g, lane, wid, a_lds,
                   s_lds, zi_lds);
  grid.sync();

  // ---- phase J: final gemm ----
  for (int t = bid; t < N_NODES / 32; t += nb)
    dev_gemm<NH * DM, true>(t, p.g, p.wpsz, p.h, p.mb, nullptr, p.out, nullptr, nullptr,
                            nullptr, lane, wid);
}

extern "C" void kernel_launch(void* const* d_in, const int* in_sizes, int n_in,
                              void* d_out, int out_size, void* d_ws, size_t ws_size,
                              hipStream_t stream) {
  P p;
  p.x = (const float*)d_in[0];
  p.srcE = (const int*)d_in[1];
  p.dstE = (const int*)d_in[2];
  p.Ws = (const float*)d_in[3];
  p.als = (const float*)d_in[4];
  p.ars = (const float*)d_in[5];
  p.bs = (const float*)d_in[6];
  p.W_last = (const float*)d_in[7];
  p.al_last = (const float*)d_in[8];
  p.ar_last = (const float*)d_in[9];
  p.b_last = (const float*)d_in[10];
  p.out = (float*)d_out;

  // ---- workspace layout ----
  float* h = (float*)d_ws;                           // 2,560,000 f
  float* elr = h + 2560000;                          // 320,000 f
  float* mb = elr + 320000;                          // 128 f
  unsigned short* hb = (unsigned short*)(mb + 128);  // 2,560,000 us
  unsigned short* feat = hb + 2560000;               // 2,560,000 us
  unsigned short* g = feat + 2560000;                // 20,480,000 us
  unsigned short* wsz = g + 20480000;                // 32,768 us
  unsigned short* wpsz = wsz + 32768;                // 131,072 us
  unsigned short* wlrsz = wpsz + 131072;             // 2,048 us
  int* deg = (int*)(wlrsz + 2048);
  int* off = deg + N_NODES;
  int* cursor = off + N_NODES + 1;
  int* csr_src = cursor + N_NODES;

  p.h = h;
  p.elr = elr;
  p.mb = mb;
  p.hb = hb;
  p.feat = feat;
  p.g = g;
  p.wsz = wsz;
  p.wpsz = wpsz;
  p.wlrsz = wlrsz;
  p.deg = deg;
  p.off = off;
  p.cursor = cursor;
  p.csr_src = csr_src;

  int maxb = 0;
  hipOccupancyMaxActiveBlocksPerMultiprocessor(&maxb, (const void*)mega, 256, 0);
  if (maxb < 1) maxb = 1;
  int nblocks = maxb * 256;  // 256 CUs on MI355X
  if (nblocks > 1536) nblocks = 1536;
  if (nblocks < 2) nblocks = 2;

  void* args[] = {&p};
  hipLaunchCooperativeKernel((const void*)mega, dim3(nblocks), dim3(256), args, 0, stream);
}

// Round 11
// 255.879 us; speedup vs baseline: 3.2049x; 3.2049x over previous
//
#include <hip/hip_runtime.h>
#include <math.h>

#define N_NODES 20000
#define N_EDGES 200000
#define DM 128
#define NH 8

typedef __attribute__((ext_vector_type(8))) short bf16x8;
typedef __attribute__((ext_vector_type(4))) float f32x4;

__device__ __forceinline__ unsigned short f2b(float f) {
  unsigned int u = __float_as_uint(f);
  unsigned int r = (u + 0x7FFFu + ((u >> 16) & 1u)) >> 16;  // RNE
  return (unsigned short)r;
}
__device__ __forceinline__ float b2f(unsigned short s) {
  return __uint_as_float(((unsigned int)s) << 16);
}

// ---------------- prep: cast + deg zero + all weight prep + ticket zero ----------------
__global__ __launch_bounds__(256) void prep_all(
    const float* __restrict__ x, float* __restrict__ h, unsigned short* __restrict__ hb,
    const float* __restrict__ Ws, unsigned short* __restrict__ wsz,
    const float* __restrict__ W_last, unsigned short* __restrict__ wpsz,
    const float* __restrict__ al_last, const float* __restrict__ ar_last,
    const float* __restrict__ b_last, unsigned short* __restrict__ wlrsz,
    float* __restrict__ mb, int* __restrict__ deg, int* __restrict__ ticket) {
  int i = blockIdx.x * 256 + threadIdx.x;
  if (i < (N_NODES * DM) / 4) {  // float4 cast
    float4 v = ((const float4*)x)[i];
    ((float4*)h)[i] = v;
    ((ushort4*)hb)[i] = make_ushort4(f2b(v.x), f2b(v.y), f2b(v.z), f2b(v.w));
  }
  if (i < N_NODES) deg[i] = 0;
  if (i == 0) *ticket = 0;
  if (i < 2 * 16384) {  // layers 0/1 B swizzle
    int layer = i >> 14;
    int r = i & 16383;
    int j = r & 7, l = (r >> 3) & 63, f = (r >> 9) & 7, ks = r >> 12;
    int k = ks * 32 + ((l >> 4) << 3) + j;
    int n = f * 16 + (l & 15);
    wsz[i] = f2b(Ws[(size_t)layer * 16384 + k * 128 + n]);
  }
  if (i < 131072) {  // last-layer B swizzle (1/8 mean folded)
    int j = i & 7, l = (i >> 3) & 63, f = (i >> 9) & 7, ks = i >> 12;
    int k = ks * 32 + ((l >> 4) << 3) + j;
    int n = f * 16 + (l & 15);
    int h_ = k >> 7, ko = k & 127;
    wpsz[i] = f2b(W_last[(size_t)ko * 1024 + h_ * 128 + n] * 0.125f);
  }
  if (i < 2048) {  // wlr fragment build
    int j = i & 7, l = (i >> 3) & 63, ks = i >> 9;
    int k = ks * 32 + ((l >> 4) << 3) + j;
    int n = l & 15;
    int hh = n & 7;
    const float* av = (n < 8) ? (al_last + hh * 128) : (ar_last + hh * 128);
    float s = 0.f;
    for (int d = 0; d < 128; ++d) s += W_last[(size_t)k * 1024 + hh * 128 + d] * av[d];
    wlrsz[i] = f2b(s);
  }
  if (i < 128) {
    float s = 0.f;
#pragma unroll
    for (int hh = 0; hh < 8; ++hh) s += b_last[hh * 128 + i];
    mb[i] = s * 0.125f;
  }
}

// ---------------- degree count + last-block prefix scan ----------------
__global__ __launch_bounds__(256) void count_scan(const int* __restrict__ dst,
                                                  int* __restrict__ deg,
                                                  int* __restrict__ off,
                                                  int* __restrict__ cursor,
                                                  int* __restrict__ ticket) {
  int e = blockIdx.x * 256 + threadIdx.x;
  if (e < N_EDGES) atomicAdd(&deg[dst[e]], 1);
  __threadfence();
  __syncthreads();  // ALL waves of this block must finish their adds before ticket
  __shared__ int lastFlag;
  if (threadIdx.x == 0) {
    int t = __hip_atomic_fetch_add(ticket, 1, __ATOMIC_ACQ_REL, __HIP_MEMORY_SCOPE_AGENT);
    lastFlag = (t == (int)gridDim.x - 1);
  }
  __syncthreads();
  if (!lastFlag) return;

  // last block performs the exclusive scan
  __shared__ int part[256];
  const int tid = threadIdx.x;
  const int NPT = (N_NODES + 255) / 256;  // 79
  int b0 = tid * NPT, b1 = min(N_NODES, b0 + NPT);
  int s = 0;
  for (int j = b0; j < b1; ++j)
    s += __hip_atomic_load(&deg[j], __ATOMIC_RELAXED, __HIP_MEMORY_SCOPE_AGENT);
  part[tid] = s;
  __syncthreads();
  for (int ofs = 1; ofs < 256; ofs <<= 1) {
    int v = (tid >= ofs) ? part[tid - ofs] : 0;
    __syncthreads();
    part[tid] += v;
    __syncthreads();
  }
  int run = (tid > 0) ? part[tid - 1] : 0;
  for (int j = b0; j < b1; ++j) {
    int d = __hip_atomic_load(&deg[j], __ATOMIC_RELAXED, __HIP_MEMORY_SCOPE_AGENT);
    off[j] = run;
    cursor[j] = run;
    run += d;
  }
  if (tid == 255) off[N_NODES] = part[255];
  if (tid == 0) __hip_atomic_store(ticket, 0, __ATOMIC_RELAXED, __HIP_MEMORY_SCOPE_AGENT);
}

// ---------------- MFMA GEMM device body ----------------
template <int K, bool LAST>
__device__ __forceinline__ void dev_gemm(int tile, const unsigned short* __restrict__ A,
                                         const unsigned short* __restrict__ Bsz,
                                         const float* __restrict__ hres,
                                         const float* __restrict__ mbv,
                                         unsigned short* __restrict__ Cb,
                                         float* __restrict__ Cf,
                                         const float* __restrict__ al,
                                         const float* __restrict__ ar,
                                         float* __restrict__ elr, int lane, int wid) {
  const int wrow = wid & 1, wc = wid >> 1;
  const int r0 = tile * 32;
  const int arow = r0 + wrow * 16 + (lane & 15);
  const int kg = lane >> 4;

  f32x4 acc[4];
#pragma unroll
  for (int fi = 0; fi < 4; ++fi) acc[fi] = {0.f, 0.f, 0.f, 0.f};

  const bf16x8* Ap = (const bf16x8*)(A + (size_t)arow * K + kg * 8);
#pragma unroll 4
  for (int ks = 0; ks < K / 32; ++ks) {
    bf16x8 a = Ap[ks * 4];
#pragma unroll
    for (int fi = 0; fi < 4; ++fi) {
      int f = wc * 4 + fi;
      bf16x8 b = *(const bf16x8*)(Bsz + (((size_t)(ks * 8 + f) * 64 + lane) << 3));
      acc[fi] = __builtin_amdgcn_mfma_f32_16x16x32_bf16(a, b, acc[fi], 0, 0, 0);
    }
  }

  const int rbase = r0 + wrow * 16 + (lane >> 4) * 4;
#pragma unroll
  for (int fi = 0; fi < 4; ++fi) {
    int col = wc * 64 + fi * 16 + (lane & 15);
#pragma unroll
    for (int r = 0; r < 4; ++r) {
      int row = rbase + r;
      float v = acc[fi][r];
      if (LAST)
        Cf[(size_t)row * DM + col] = v + hres[(size_t)row * DM + col] + mbv[col];
      else
        Cb[(size_t)row * DM + col] = f2b(v);
    }
  }

  if (!LAST) {
#pragma unroll
    for (int fi = 0; fi < 4; ++fi) {
      int hh = wc * 4 + fi;
      float alv = al[hh * 16 + (lane & 15)];
      float arv = ar[hh * 16 + (lane & 15)];
#pragma unroll
      for (int r = 0; r < 4; ++r) {
        float pl = acc[fi][r] * alv;
        float pr = acc[fi][r] * arv;
#pragma unroll
        for (int msk = 1; msk < 16; msk <<= 1) {
          pl += __shfl_xor(pl, msk, 64);
          pr += __shfl_xor(pr, msk, 64);
        }
        if ((lane & 15) == 0) {
          int row = rbase + r;
          elr[row * 16 + hh] = pl;
          elr[row * 16 + 8 + hh] = pr;
        }
      }
    }
  }
}

// layer0 GEMM || CSR scatter (independent outputs, both consumed by fused0)
__global__ __launch_bounds__(256) void gemm0_scatter(
    const unsigned short* __restrict__ A, const unsigned short* __restrict__ Bsz,
    unsigned short* __restrict__ Cb, const float* __restrict__ al,
    const float* __restrict__ ar, float* __restrict__ elr, const int* __restrict__ srcE,
    const int* __restrict__ dstE, int* __restrict__ cursor, int* __restrict__ csr_src) {
  const int bid = blockIdx.x;
  if (bid < N_NODES / 32) {
    dev_gemm<DM, false>(bid, A, Bsz, nullptr, nullptr, Cb, nullptr, al, ar, elr,
                        threadIdx.x & 63, threadIdx.x >> 6);
  } else {
    int e = (bid - N_NODES / 32) * 256 + threadIdx.x;
    if (e < N_EDGES) {
      int pos = atomicAdd(&cursor[dstE[e]], 1);
      csr_src[pos] = srcE[e];
    }
  }
}

template <int K, bool LAST>
__global__ __launch_bounds__(256) void gemm_mfma(
    const unsigned short* __restrict__ A, const unsigned short* __restrict__ Bsz,
    const float* __restrict__ hres, const float* __restrict__ mbv,
    unsigned short* __restrict__ Cb, float* __restrict__ Cf,
    const float* __restrict__ al, const float* __restrict__ ar, float* __restrict__ elr) {
  dev_gemm<K, LAST>(blockIdx.x, A, Bsz, hres, mbv, Cb, Cf, al, ar, elr, threadIdx.x & 63,
                    threadIdx.x >> 6);
}

// ---------------- layers 0/1: fused softmax+agg (+optional elr_last epilogue) ----------------
// ELR epilogue writes to elr_out (a SEPARATE buffer from the elr being read).
template <bool ELR>
__global__ __launch_bounds__(256) void fused_small(
    const int* __restrict__ off, const int* __restrict__ csr_src,
    const unsigned short* __restrict__ feat, const float* __restrict__ elr,
    const float* __restrict__ bias, float* __restrict__ h, unsigned short* __restrict__ hb,
    const unsigned short* __restrict__ wlrsz, float* __restrict__ elr_out) {
  __shared__ float a_lds[4][64];
  __shared__ int s_lds[4][8];
  __shared__ float zi_lds[4][8];
  __shared__ __align__(16) unsigned short nh_lds[4][128];
  const int wid = threadIdx.x >> 6;
  const int t = blockIdx.x * 4 + wid;
  const int lane = threadIdx.x & 63;
  const int e_loc = lane >> 3, hh = lane & 7;
  const int hg = lane >> 3;  // head for dims 2*lane, 2*lane+1
  const int beg = off[t], end = off[t + 1];
  const float ert = elr[t * 16 + 8 + hh];

  int e = beg + e_loc;
  bool val = e < end;
  int s = val ? csr_src[e] : 0;
  float xl = val ? elr[s * 16 + hh] : 0.f;

  float z = 0.f, acc0 = 0.f, acc1 = 0.f;
  for (int base = beg; base < end; base += 8) {
    float ex = 0.f;
    if (val) {
      float xv = xl + ert;
      xv = xv > 0.f ? xv : 0.2f * xv;
      ex = __expf(xv);
    }
    a_lds[wid][lane] = ex;
    if (hh == 0) s_lds[wid][e_loc] = s;
    __builtin_amdgcn_wave_barrier();
    asm volatile("s_waitcnt lgkmcnt(0)" ::: "memory");
    z += ex;
    int en = base + 8 + e_loc;
    bool valn = en < end;
    int sn = valn ? csr_src[en] : 0;
    float xln = valn ? elr[sn * 16 + hh] : 0.f;
    int n = min(8, end - base);
    for (int e2 = 0; e2 < n; ++e2) {
      int s2 = s_lds[wid][e2];
      float a = a_lds[wid][e2 * 8 + hg];
      unsigned int hv = *(const unsigned int*)&feat[(size_t)s2 * 128 + 2 * lane];
      acc0 += a * b2f((unsigned short)(hv & 0xffffu));
      acc1 += a * b2f((unsigned short)(hv >> 16));
    }
    __builtin_amdgcn_wave_barrier();
    s = sn;
    xl = xln;
    val = valn;
  }
  z += __shfl_xor(z, 8, 64);
  z += __shfl_xor(z, 16, 64);
  z += __shfl_xor(z, 32, 64);
  if (e_loc == 0) zi_lds[wid][hh] = (z > 0.f) ? 1.f / z : 0.f;
  __builtin_amdgcn_wave_barrier();
  asm volatile("s_waitcnt lgkmcnt(0)" ::: "memory");
  float zi = zi_lds[wid][hg];

  float2 bv = *(const float2*)&bias[2 * lane];
  float v0 = acc0 * zi + bv.x;
  float v1 = acc1 * zi + bv.y;
  v0 = v0 > 0.f ? v0 : expm1f(v0);
  v1 = v1 > 0.f ? v1 : expm1f(v1);
  size_t idx = (size_t)t * 128 + 2 * lane;
  float2 hv = *(const float2*)&h[idx];
  float nh0 = hv.x + v0;
  float nh1 = hv.y + v1;
  *(float2*)&h[idx] = make_float2(nh0, nh1);
  unsigned short b0 = f2b(nh0), b1 = f2b(nh1);
  *(ushort2*)&hb[idx] = make_ushort2(b0, b1);

  if (ELR) {
    // elr_last fused: elr_out[t][0..15] = nh @ [wl|wr] via one MFMA chain
    *(ushort2*)&nh_lds[wid][2 * lane] = make_ushort2(b0, b1);
    __builtin_amdgcn_wave_barrier();
    asm volatile("s_waitcnt lgkmcnt(0)" ::: "memory");
    const int kg = lane >> 4;
    f32x4 acc = {0.f, 0.f, 0.f, 0.f};
#pragma unroll
    for (int ks = 0; ks < 4; ++ks) {
      bf16x8 a = *(const bf16x8*)&nh_lds[wid][ks * 32 + kg * 8];
      bf16x8 b = *(const bf16x8*)(wlrsz + (((size_t)ks * 64 + lane) << 3));
      acc = __builtin_amdgcn_mfma_f32_16x16x32_bf16(a, b, acc, 0, 0, 0);
    }
    if (lane < 16) elr_out[t * 16 + lane] = acc[0];
  }
}

// ---------------- last layer: fused softmax+agg, single pass, pipelined ----------------
__global__ __launch_bounds__(256) void fused_last(
    const int* __restrict__ off, const int* __restrict__ csr_src,
    const unsigned short* __restrict__ hb, const float* __restrict__ elr,
    unsigned short* __restrict__ g) {
  __shared__ float a_lds[4][64];
  __shared__ int s_lds[4][8];
  __shared__ float zi_lds[4][8];
  const int wid = threadIdx.x >> 6;
  const int t = blockIdx.x * 4 + wid;
  const int lane = threadIdx.x & 63;
  const int e_loc = lane >> 3, hh = lane & 7;
  const int beg = off[t], end = off[t + 1];
  const float ert = elr[t * 16 + 8 + hh];

  int e = beg + e_loc;
  bool val = e < end;
  int s = val ? csr_src[e] : 0;
  float xl = val ? elr[s * 16 + hh] : 0.f;

  float z = 0.f;
  float accA[8], accB[8];
#pragma unroll
  for (int k = 0; k < 8; ++k) accA[k] = accB[k] = 0.f;

  for (int base = beg; base < end; base += 8) {
    float ex = 0.f;
    if (val) {
      float xv = xl + ert;
      xv = xv > 0.f ? xv : 0.2f * xv;
      ex = __expf(xv);
    }
    a_lds[wid][lane] = ex;
    if (hh == 0) s_lds[wid][e_loc] = s;
    __builtin_amdgcn_wave_barrier();
    asm volatile("s_waitcnt lgkmcnt(0)" ::: "memory");
    z += ex;
    int en = base + 8 + e_loc;
    bool valn = en < end;
    int sn = valn ? csr_src[en] : 0;
    float xln = valn ? elr[sn * 16 + hh] : 0.f;
    int n = min(8, end - base);
    for (int e2 = 0; e2 < n; ++e2) {
      int s2 = s_lds[wid][e2];
      float4 pa = *(const float4*)&a_lds[wid][e2 * 8];
      float4 pb = *(const float4*)&a_lds[wid][e2 * 8 + 4];
      unsigned int hv = *(const unsigned int*)&hb[(size_t)s2 * 128 + 2 * lane];
      float h0 = b2f((unsigned short)(hv & 0xffffu));
      float h1 = b2f((unsigned short)(hv >> 16));
      accA[0] += pa.x * h0; accB[0] += pa.x * h1;
      accA[1] += pa.y * h0; accB[1] += pa.y * h1;
      accA[2] += pa.z * h0; accB[2] += pa.z * h1;
      accA[3] += pa.w * h0; accB[3] += pa.w * h1;
      accA[4] += pb.x * h0; accB[4] += pb.x * h1;
      accA[5] += pb.y * h0; accB[5] += pb.y * h1;
      accA[6] += pb.z * h0; accB[6] += pb.z * h1;
      accA[7] += pb.w * h0; accB[7] += pb.w * h1;
    }
    __builtin_amdgcn_wave_barrier();
    s = sn;
    xl = xln;
    val = valn;
  }
  z += __shfl_xor(z, 8, 64);
  z += __shfl_xor(z, 16, 64);
  z += __shfl_xor(z, 32, 64);
  if (e_loc == 0) zi_lds[wid][hh] = (z > 0.f) ? 1.f / z : 0.f;
  __builtin_amdgcn_wave_barrier();
  asm volatile("s_waitcnt lgkmcnt(0)" ::: "memory");
  float4 zia = *(const float4*)&zi_lds[wid][0];
  float4 zib = *(const float4*)&zi_lds[wid][4];
  float ziv[8] = {zia.x, zia.y, zia.z, zia.w, zib.x, zib.y, zib.z, zib.w};
#pragma unroll
  for (int h2 = 0; h2 < 8; ++h2) {
    *(ushort2*)&g[(size_t)t * 1024 + h2 * 128 + 2 * lane] =
        make_ushort2(f2b(accA[h2] * ziv[h2]), f2b(accB[h2] * ziv[h2]));
  }
}

extern "C" void kernel_launch(void* const* d_in, const int* in_sizes, int n_in,
                              void* d_out, int out_size, void* d_ws, size_t ws_size,
                              hipStream_t stream) {
  const float* x = (const float*)d_in[0];
  const int* src = (const int*)d_in[1];
  const int* dst = (const int*)d_in[2];
  const float* Ws = (const float*)d_in[3];
  const float* als = (const float*)d_in[4];
  const float* ars = (const float*)d_in[5];
  const float* bs = (const float*)d_in[6];
  const float* W_last = (const float*)d_in[7];
  const float* al_last = (const float*)d_in[8];
  const float* ar_last = (const float*)d_in[9];
  const float* b_last = (const float*)d_in[10];
  float* out = (float*)d_out;

  // ---- workspace layout ----
  float* h = (float*)d_ws;                           // 2,560,000 f
  float* elr = h + 2560000;                          // 320,000 f
  float* elr2 = elr + 320000;                        // 320,000 f (last-layer scores)
  float* mb = elr2 + 320000;                         // 128 f
  unsigned short* hb = (unsigned short*)(mb + 128);  // 2,560,000 us
  unsigned short* feat = hb + 2560000;               // 2,560,000 us
  unsigned short* g = feat + 2560000;                // 20,480,000 us
  unsigned short* wsz = g + 20480000;                // 32,768 us
  unsigned short* wpsz = wsz + 32768;                // 131,072 us
  unsigned short* wlrsz = wpsz + 131072;             // 2,048 us
  int* deg = (int*)(wlrsz + 2048);
  int* off = deg + N_NODES;
  int* cursor = off + N_NODES + 1;
  int* csr_src = cursor + N_NODES;
  int* ticket = csr_src + N_EDGES;

  const int GB = N_NODES / 32;            // 625
  const int FB = N_NODES / 4;             // 5000
  const int EB = (N_EDGES + 255) / 256;   // 782

  prep_all<<<(N_NODES * DM / 4 + 255) / 256, 256, 0, stream>>>(
      x, h, hb, Ws, wsz, W_last, wpsz, al_last, ar_last, b_last, wlrsz, mb, deg, ticket);
  count_scan<<<EB, 256, 0, stream>>>(dst, deg, off, cursor, ticket);
  gemm0_scatter<<<GB + EB, 256, 0, stream>>>(hb, wsz, feat, als, ars, elr, src, dst,
                                             cursor, csr_src);
  fused_small<false><<<FB, 256, 0, stream>>>(off, csr_src, feat, elr, bs, h, hb, nullptr,
                                             nullptr);
  gemm_mfma<DM, false><<<GB, 256, 0, stream>>>(hb, wsz + 16384, nullptr, nullptr, feat,
                                               nullptr, als + 128, ars + 128, elr);
  fused_small<true><<<FB, 256, 0, stream>>>(off, csr_src, feat, elr, bs + 128, h, hb,
                                            wlrsz, elr2);
  fused_last<<<FB, 256, 0, stream>>>(off, csr_src, hb, elr2, g);
  gemm_mfma<NH * DM, true><<<GB, 256, 0, stream>>>(g, wpsz, h, mb, nullptr, out, nullptr,
                                                   nullptr, nullptr);
}

// Round 12
// 255.279 us; speedup vs baseline: 3.2124x; 1.0024x over previous
//
#include <hip/hip_runtime.h>
#include <math.h>

#define N_NODES 20000
#define N_EDGES 200000
#define DM 128
#define NH 8

typedef __attribute__((ext_vector_type(8))) short bf16x8;
typedef __attribute__((ext_vector_type(4))) float f32x4;

__device__ __forceinline__ unsigned short f2b(float f) {
  unsigned int u = __float_as_uint(f);
  unsigned int r = (u + 0x7FFFu + ((u >> 16) & 1u)) >> 16;  // RNE
  return (unsigned short)r;
}
__device__ __forceinline__ float b2f(unsigned short s) {
  return __uint_as_float(((unsigned int)s) << 16);
}

// ---------------- prep: cast + deg zero + all weight prep + ticket zero ----------------
__global__ __launch_bounds__(256) void prep_all(
    const float* __restrict__ x, float* __restrict__ h, unsigned short* __restrict__ hb,
    const float* __restrict__ Ws, unsigned short* __restrict__ wsz,
    const float* __restrict__ W_last, unsigned short* __restrict__ wpsz,
    const float* __restrict__ al_last, const float* __restrict__ ar_last,
    const float* __restrict__ b_last, unsigned short* __restrict__ wlrsz,
    float* __restrict__ mb, int* __restrict__ deg, int* __restrict__ ticket) {
  int i = blockIdx.x * 256 + threadIdx.x;
  if (i < (N_NODES * DM) / 4) {  // float4 cast
    float4 v = ((const float4*)x)[i];
    ((float4*)h)[i] = v;
    ((ushort4*)hb)[i] = make_ushort4(f2b(v.x), f2b(v.y), f2b(v.z), f2b(v.w));
  }
  if (i < N_NODES) deg[i] = 0;
  if (i == 0) *ticket = 0;
  if (i < 2 * 16384) {  // layers 0/1 B swizzle
    int layer = i >> 14;
    int r = i & 16383;
    int j = r & 7, l = (r >> 3) & 63, f = (r >> 9) & 7, ks = r >> 12;
    int k = ks * 32 + ((l >> 4) << 3) + j;
    int n = f * 16 + (l & 15);
    wsz[i] = f2b(Ws[(size_t)layer * 16384 + k * 128 + n]);
  }
  if (i < 131072) {  // last-layer B swizzle (1/8 mean folded)
    int j = i & 7, l = (i >> 3) & 63, f = (i >> 9) & 7, ks = i >> 12;
    int k = ks * 32 + ((l >> 4) << 3) + j;
    int n = f * 16 + (l & 15);
    int h_ = k >> 7, ko = k & 127;
    wpsz[i] = f2b(W_last[(size_t)ko * 1024 + h_ * 128 + n] * 0.125f);
  }
  if (i < 2048) {  // wlr fragment build
    int j = i & 7, l = (i >> 3) & 63, ks = i >> 9;
    int k = ks * 32 + ((l >> 4) << 3) + j;
    int n = l & 15;
    int hh = n & 7;
    const float* av = (n < 8) ? (al_last + hh * 128) : (ar_last + hh * 128);
    float s = 0.f;
    for (int d = 0; d < 128; ++d) s += W_last[(size_t)k * 1024 + hh * 128 + d] * av[d];
    wlrsz[i] = f2b(s);
  }
  if (i < 128) {
    float s = 0.f;
#pragma unroll
    for (int hh = 0; hh < 8; ++hh) s += b_last[hh * 128 + i];
    mb[i] = s * 0.125f;
  }
}

// ---------------- degree count + last-block prefix scan ----------------
__global__ __launch_bounds__(256) void count_scan(const int* __restrict__ dst,
                                                  int* __restrict__ deg,
                                                  int* __restrict__ off,
                                                  int* __restrict__ cursor,
                                                  int* __restrict__ ticket) {
  int e = blockIdx.x * 256 + threadIdx.x;
  if (e < N_EDGES) atomicAdd(&deg[dst[e]], 1);
  __threadfence();
  __syncthreads();  // ALL waves of this block must finish their adds before ticket
  __shared__ int lastFlag;
  if (threadIdx.x == 0) {
    int t = __hip_atomic_fetch_add(ticket, 1, __ATOMIC_ACQ_REL, __HIP_MEMORY_SCOPE_AGENT);
    lastFlag = (t == (int)gridDim.x - 1);
  }
  __syncthreads();
  if (!lastFlag) return;

  // last block performs the exclusive scan
  __shared__ int part[256];
  const int tid = threadIdx.x;
  const int NPT = (N_NODES + 255) / 256;  // 79
  int b0 = tid * NPT, b1 = min(N_NODES, b0 + NPT);
  int s = 0;
  for (int j = b0; j < b1; ++j)
    s += __hip_atomic_load(&deg[j], __ATOMIC_RELAXED, __HIP_MEMORY_SCOPE_AGENT);
  part[tid] = s;
  __syncthreads();
  for (int ofs = 1; ofs < 256; ofs <<= 1) {
    int v = (tid >= ofs) ? part[tid - ofs] : 0;
    __syncthreads();
    part[tid] += v;
    __syncthreads();
  }
  int run = (tid > 0) ? part[tid - 1] : 0;
  for (int j = b0; j < b1; ++j) {
    int d = __hip_atomic_load(&deg[j], __ATOMIC_RELAXED, __HIP_MEMORY_SCOPE_AGENT);
    off[j] = run;
    cursor[j] = run;
    run += d;
  }
  if (tid == 255) off[N_NODES] = part[255];
  if (tid == 0) __hip_atomic_store(ticket, 0, __ATOMIC_RELAXED, __HIP_MEMORY_SCOPE_AGENT);
}

// ---------------- MFMA GEMM device body ----------------
template <int K, bool LAST>
__device__ __forceinline__ void dev_gemm(int tile, const unsigned short* __restrict__ A,
                                         const unsigned short* __restrict__ Bsz,
                                         const float* __restrict__ hres,
                                         const float* __restrict__ mbv,
                                         unsigned short* __restrict__ Cb,
                                         float* __restrict__ Cf,
                                         const float* __restrict__ al,
                                         const float* __restrict__ ar,
                                         float* __restrict__ elr, int lane, int wid) {
  const int wrow = wid & 1, wc = wid >> 1;
  const int r0 = tile * 32;
  const int arow = r0 + wrow * 16 + (lane & 15);
  const int kg = lane >> 4;

  f32x4 acc[4];
#pragma unroll
  for (int fi = 0; fi < 4; ++fi) acc[fi] = {0.f, 0.f, 0.f, 0.f};

  const bf16x8* Ap = (const bf16x8*)(A + (size_t)arow * K + kg * 8);
#pragma unroll 4
  for (int ks = 0; ks < K / 32; ++ks) {
    bf16x8 a = Ap[ks * 4];
#pragma unroll
    for (int fi = 0; fi < 4; ++fi) {
      int f = wc * 4 + fi;
      bf16x8 b = *(const bf16x8*)(Bsz + (((size_t)(ks * 8 + f) * 64 + lane) << 3));
      acc[fi] = __builtin_amdgcn_mfma_f32_16x16x32_bf16(a, b, acc[fi], 0, 0, 0);
    }
  }

  const int rbase = r0 + wrow * 16 + (lane >> 4) * 4;
#pragma unroll
  for (int fi = 0; fi < 4; ++fi) {
    int col = wc * 64 + fi * 16 + (lane & 15);
#pragma unroll
    for (int r = 0; r < 4; ++r) {
      int row = rbase + r;
      float v = acc[fi][r];
      if (LAST)
        Cf[(size_t)row * DM + col] = v + hres[(size_t)row * DM + col] + mbv[col];
      else
        Cb[(size_t)row * DM + col] = f2b(v);
    }
  }

  if (!LAST) {
#pragma unroll
    for (int fi = 0; fi < 4; ++fi) {
      int hh = wc * 4 + fi;
      float alv = al[hh * 16 + (lane & 15)];
      float arv = ar[hh * 16 + (lane & 15)];
#pragma unroll
      for (int r = 0; r < 4; ++r) {
        float pl = acc[fi][r] * alv;
        float pr = acc[fi][r] * arv;
#pragma unroll
        for (int msk = 1; msk < 16; msk <<= 1) {
          pl += __shfl_xor(pl, msk, 64);
          pr += __shfl_xor(pr, msk, 64);
        }
        if ((lane & 15) == 0) {
          int row = rbase + r;
          elr[row * 16 + hh] = pl;
          elr[row * 16 + 8 + hh] = pr;
        }
      }
    }
  }
}

// layer0 GEMM || CSR scatter (independent outputs, both consumed by fused0)
__global__ __launch_bounds__(256) void gemm0_scatter(
    const unsigned short* __restrict__ A, const unsigned short* __restrict__ Bsz,
    unsigned short* __restrict__ Cb, const float* __restrict__ al,
    const float* __restrict__ ar, float* __restrict__ elr, const int* __restrict__ srcE,
    const int* __restrict__ dstE, int* __restrict__ cursor, int* __restrict__ csr_src) {
  const int bid = blockIdx.x;
  if (bid < N_NODES / 32) {
    dev_gemm<DM, false>(bid, A, Bsz, nullptr, nullptr, Cb, nullptr, al, ar, elr,
                        threadIdx.x & 63, threadIdx.x >> 6);
  } else {
    int e = (bid - N_NODES / 32) * 256 + threadIdx.x;
    if (e < N_EDGES) {
      int pos = atomicAdd(&cursor[dstE[e]], 1);
      csr_src[pos] = srcE[e];
    }
  }
}

template <int K, bool LAST>
__global__ __launch_bounds__(256) void gemm_mfma(
    const unsigned short* __restrict__ A, const unsigned short* __restrict__ Bsz,
    const float* __restrict__ hres, const float* __restrict__ mbv,
    unsigned short* __restrict__ Cb, float* __restrict__ Cf,
    const float* __restrict__ al, const float* __restrict__ ar, float* __restrict__ elr) {
  dev_gemm<K, LAST>(blockIdx.x, A, Bsz, hres, mbv, Cb, Cf, al, ar, elr, threadIdx.x & 63,
                    threadIdx.x >> 6);
}

// ---------------- layers 0/1: fused softmax+agg (+optional elr_last epilogue) ----------------
// ELR epilogue writes to elr_out (a SEPARATE buffer from the elr being read).
template <bool ELR>
__global__ __launch_bounds__(256) void fused_small(
    const int* __restrict__ off, const int* __restrict__ csr_src,
    const unsigned short* __restrict__ feat, const float* __restrict__ elr,
    const float* __restrict__ bias, float* __restrict__ h, unsigned short* __restrict__ hb,
    const unsigned short* __restrict__ wlrsz, float* __restrict__ elr_out) {
  __shared__ float a_lds[4][64];
  __shared__ int s_lds[4][8];
  __shared__ float zi_lds[4][8];
  __shared__ __align__(16) unsigned short nh_lds[4][128];
  const int wid = threadIdx.x >> 6;
  const int t = blockIdx.x * 4 + wid;
  const int lane = threadIdx.x & 63;
  const int e_loc = lane >> 3, hh = lane & 7;
  const int hg = lane >> 3;  // head for dims 2*lane, 2*lane+1
  const int beg = off[t], end = off[t + 1];
  const float ert = elr[t * 16 + 8 + hh];

  int e = beg + e_loc;
  bool val = e < end;
  int s = val ? csr_src[e] : 0;
  float xl = val ? elr[s * 16 + hh] : 0.f;

  float z = 0.f, acc0 = 0.f, acc1 = 0.f;
  for (int base = beg; base < end; base += 8) {
    float ex = 0.f;
    if (val) {
      float xv = xl + ert;
      xv = xv > 0.f ? xv : 0.2f * xv;
      ex = __expf(xv);
    }
    a_lds[wid][lane] = ex;
    if (hh == 0) s_lds[wid][e_loc] = s;
    __builtin_amdgcn_wave_barrier();
    asm volatile("s_waitcnt lgkmcnt(0)" ::: "memory");
    z += ex;
    int en = base + 8 + e_loc;
    bool valn = en < end;
    int sn = valn ? csr_src[en] : 0;
    float xln = valn ? elr[sn * 16 + hh] : 0.f;
    int n = min(8, end - base);
    for (int e2 = 0; e2 < n; ++e2) {
      int s2 = s_lds[wid][e2];
      float a = a_lds[wid][e2 * 8 + hg];
      unsigned int hv = *(const unsigned int*)&feat[(size_t)s2 * 128 + 2 * lane];
      acc0 += a * b2f((unsigned short)(hv & 0xffffu));
      acc1 += a * b2f((unsigned short)(hv >> 16));
    }
    __builtin_amdgcn_wave_barrier();
    s = sn;
    xl = xln;
    val = valn;
  }
  z += __shfl_xor(z, 8, 64);
  z += __shfl_xor(z, 16, 64);
  z += __shfl_xor(z, 32, 64);
  if (e_loc == 0) zi_lds[wid][hh] = (z > 0.f) ? 1.f / z : 0.f;
  __builtin_amdgcn_wave_barrier();
  asm volatile("s_waitcnt lgkmcnt(0)" ::: "memory");
  float zi = zi_lds[wid][hg];

  float2 bv = *(const float2*)&bias[2 * lane];
  float v0 = acc0 * zi + bv.x;
  float v1 = acc1 * zi + bv.y;
  v0 = v0 > 0.f ? v0 : expm1f(v0);
  v1 = v1 > 0.f ? v1 : expm1f(v1);
  size_t idx = (size_t)t * 128 + 2 * lane;
  float2 hv = *(const float2*)&h[idx];
  float nh0 = hv.x + v0;
  float nh1 = hv.y + v1;
  *(float2*)&h[idx] = make_float2(nh0, nh1);
  unsigned short b0 = f2b(nh0), b1 = f2b(nh1);
  *(ushort2*)&hb[idx] = make_ushort2(b0, b1);

  if (ELR) {
    // elr_last fused: elr_out[t][0..15] = nh @ [wl|wr] via one MFMA chain
    *(ushort2*)&nh_lds[wid][2 * lane] = make_ushort2(b0, b1);
    __builtin_amdgcn_wave_barrier();
    asm volatile("s_waitcnt lgkmcnt(0)" ::: "memory");
    const int kg = lane >> 4;
    f32x4 acc = {0.f, 0.f, 0.f, 0.f};
#pragma unroll
    for (int ks = 0; ks < 4; ++ks) {
      bf16x8 a = *(const bf16x8*)&nh_lds[wid][ks * 32 + kg * 8];
      bf16x8 b = *(const bf16x8*)(wlrsz + (((size_t)ks * 64 + lane) << 3));
      acc = __builtin_amdgcn_mfma_f32_16x16x32_bf16(a, b, acc, 0, 0, 0);
    }
    if (lane < 16) elr_out[t * 16 + lane] = acc[0];
  }
}

// ---------------- last layer: fused softmax+agg, single pass, pipelined ----------------
__global__ __launch_bounds__(256) void fused_last(
    const int* __restrict__ off, const int* __restrict__ csr_src,
    const unsigned short* __restrict__ hb, const float* __restrict__ elr,
    unsigned short* __restrict__ g) {
  __shared__ float a_lds[4][64];
  __shared__ int s_lds[4][8];
  __shared__ float zi_lds[4][8];
  const int wid = threadIdx.x >> 6;
  const int t = blockIdx.x * 4 + wid;
  const int lane = threadIdx.x & 63;
  const int e_loc = lane >> 3, hh = lane & 7;
  const int beg = off[t], end = off[t + 1];
  const float ert = elr[t * 16 + 8 + hh];

  int e = beg + e_loc;
  bool val = e < end;
  int s = val ? csr_src[e] : 0;
  float xl = val ? elr[s * 16 + hh] : 0.f;

  float z = 0.f;
  float accA[8], accB[8];
#pragma unroll
  for (int k = 0; k < 8; ++k) accA[k] = accB[k] = 0.f;

  for (int base = beg; base < end; base += 8) {
    float ex = 0.f;
    if (val) {
      float xv = xl + ert;
      xv = xv > 0.f ? xv : 0.2f * xv;
      ex = __expf(xv);
    }
    a_lds[wid][lane] = ex;
    if (hh == 0) s_lds[wid][e_loc] = s;
    __builtin_amdgcn_wave_barrier();
    asm volatile("s_waitcnt lgkmcnt(0)" ::: "memory");
    z += ex;
    int en = base + 8 + e_loc;
    bool valn = en < end;
    int sn = valn ? csr_src[en] : 0;
    float xln = valn ? elr[sn * 16 + hh] : 0.f;
    int n = min(8, end - base);
    for (int e2 = 0; e2 < n; ++e2) {
      int s2 = s_lds[wid][e2];
      float4 pa = *(const float4*)&a_lds[wid][e2 * 8];
      float4 pb = *(const float4*)&a_lds[wid][e2 * 8 + 4];
      unsigned int hv = *(const unsigned int*)&hb[(size_t)s2 * 128 + 2 * lane];
      float h0 = b2f((unsigned short)(hv & 0xffffu));
      float h1 = b2f((unsigned short)(hv >> 16));
      accA[0] += pa.x * h0; accB[0] += pa.x * h1;
      accA[1] += pa.y * h0; accB[1] += pa.y * h1;
      accA[2] += pa.z * h0; accB[2] += pa.z * h1;
      accA[3] += pa.w * h0; accB[3] += pa.w * h1;
      accA[4] += pb.x * h0; accB[4] += pb.x * h1;
      accA[5] += pb.y * h0; accB[5] += pb.y * h1;
      accA[6] += pb.z * h0; accB[6] += pb.z * h1;
      accA[7] += pb.w * h0; accB[7] += pb.w * h1;
    }
    __builtin_amdgcn_wave_barrier();
    s = sn;
    xl = xln;
    val = valn;
  }
  z += __shfl_xor(z, 8, 64);
  z += __shfl_xor(z, 16, 64);
  z += __shfl_xor(z, 32, 64);
  if (e_loc == 0) zi_lds[wid][hh] = (z > 0.f) ? 1.f / z : 0.f;
  __builtin_amdgcn_wave_barrier();
  asm volatile("s_waitcnt lgkmcnt(0)" ::: "memory");
  float4 zia = *(const float4*)&zi_lds[wid][0];
  float4 zib = *(const float4*)&zi_lds[wid][4];
  float ziv[8] = {zia.x, zia.y, zia.z, zia.w, zib.x, zib.y, zib.z, zib.w};
#pragma unroll
  for (int h2 = 0; h2 < 8; ++h2) {
    *(ushort2*)&g[(size_t)t * 1024 + h2 * 128 + 2 * lane] =
        make_ushort2(f2b(accA[h2] * ziv[h2]), f2b(accB[h2] * ziv[h2]));
  }
}

extern "C" void kernel_launch(void* const* d_in, const int* in_sizes, int n_in,
                              void* d_out, int out_size, void* d_ws, size_t ws_size,
                              hipStream_t stream) {
  const float* x = (const float*)d_in[0];
  const int* src = (const int*)d_in[1];
  const int* dst = (const int*)d_in[2];
  const float* Ws = (const float*)d_in[3];
  const float* als = (const float*)d_in[4];
  const float* ars = (const float*)d_in[5];
  const float* bs = (const float*)d_in[6];
  const float* W_last = (const float*)d_in[7];
  const float* al_last = (const float*)d_in[8];
  const float* ar_last = (const float*)d_in[9];
  const float* b_last = (const float*)d_in[10];
  float* out = (float*)d_out;

  // ---- workspace layout ----
  float* h = (float*)d_ws;                           // 2,560,000 f
  float* elr = h + 2560000;                          // 320,000 f
  float* elr2 = elr + 320000;                        // 320,000 f (last-layer scores)
  float* mb = elr2 + 320000;                         // 128 f
  unsigned short* hb = (unsigned short*)(mb + 128);  // 2,560,000 us
  unsigned short* feat = hb + 2560000;               // 2,560,000 us
  unsigned short* g = feat + 2560000;                // 20,480,000 us
  unsigned short* wsz = g + 20480000;                // 32,768 us
  unsigned short* wpsz = wsz + 32768;                // 131,072 us
  unsigned short* wlrsz = wpsz + 131072;             // 2,048 us
  int* deg = (int*)(wlrsz + 2048);
  int* off = deg + N_NODES;
  int* cursor = off + N_NODES + 1;
  int* csr_src = cursor + N_NODES;
  int* ticket = csr_src + N_EDGES;

  const int GB = N_NODES / 32;            // 625
  const int FB = N_NODES / 4;             // 5000
  const int EB = (N_EDGES + 255) / 256;   // 782

  prep_all<<<(N_NODES * DM / 4 + 255) / 256, 256, 0, stream>>>(
      x, h, hb, Ws, wsz, W_last, wpsz, al_last, ar_last, b_last, wlrsz, mb, deg, ticket);
  count_scan<<<EB, 256, 0, stream>>>(dst, deg, off, cursor, ticket);
  gemm0_scatter<<<GB + EB, 256, 0, stream>>>(hb, wsz, feat, als, ars, elr, src, dst,
                                             cursor, csr_src);
  fused_small<false><<<FB, 256, 0, stream>>>(off, csr_src, feat, elr, bs, h, hb, nullptr,
                                             nullptr);
  gemm_mfma<DM, false><<<GB, 256, 0, stream>>>(hb, wsz + 16384, nullptr, nullptr, feat,
                                               nullptr, als + 128, ars + 128, elr);
  fused_small<true><<<FB, 256, 0, stream>>>(off, csr_src, feat, elr, bs + 128, h, hb,
                                            wlrsz, elr2);
  fused_last<<<FB, 256, 0, stream>>>(off, csr_src, hb, elr2, g);
  gemm_mfma<NH * DM, true><<<GB, 256, 0, stream>>>(g, wpsz, h, mb, nullptr, out, nullptr,
                                                   nullptr, nullptr);
}

// Round 13
// 218.945 us; speedup vs baseline: 3.7455x; 1.1660x over previous
//
#include <hip/hip_runtime.h>
#include <math.h>

#define N_NODES 20000
#define N_EDGES 200000
#define DM 128
#define NH 8

typedef __attribute__((ext_vector_type(8))) short bf16x8;
typedef __attribute__((ext_vector_type(4))) float f32x4;

__device__ __forceinline__ unsigned short f2b(float f) {
  unsigned int u = __float_as_uint(f);
  unsigned int r = (u + 0x7FFFu + ((u >> 16) & 1u)) >> 16;  // RNE
  return (unsigned short)r;
}
__device__ __forceinline__ float b2f(unsigned short s) {
  return __uint_as_float(((unsigned int)s) << 16);
}

// ---------------- prep: cast + deg zero + all weight prep + ticket zero ----------------
__global__ __launch_bounds__(256) void prep_all(
    const float* __restrict__ x, float* __restrict__ h, unsigned short* __restrict__ hb,
    const float* __restrict__ Ws, unsigned short* __restrict__ wsz,
    const float* __restrict__ W_last, unsigned short* __restrict__ wpsz,
    const float* __restrict__ al_last, const float* __restrict__ ar_last,
    const float* __restrict__ b_last, unsigned short* __restrict__ wlrsz,
    float* __restrict__ mb, int* __restrict__ deg, int* __restrict__ ticket) {
  int i = blockIdx.x * 256 + threadIdx.x;
  if (i < (N_NODES * DM) / 4) {  // float4 cast
    float4 v = ((const float4*)x)[i];
    ((float4*)h)[i] = v;
    ((ushort4*)hb)[i] = make_ushort4(f2b(v.x), f2b(v.y), f2b(v.z), f2b(v.w));
  }
  if (i < N_NODES) deg[i] = 0;
  if (i == 0) *ticket = 0;
  if (i < 2 * 16384) {  // layers 0/1 B swizzle
    int layer = i >> 14;
    int r = i & 16383;
    int j = r & 7, l = (r >> 3) & 63, f = (r >> 9) & 7, ks = r >> 12;
    int k = ks * 32 + ((l >> 4) << 3) + j;
    int n = f * 16 + (l & 15);
    wsz[i] = f2b(Ws[(size_t)layer * 16384 + k * 128 + n]);
  }
  if (i < 131072) {  // last-layer B swizzle (1/8 mean folded)
    int j = i & 7, l = (i >> 3) & 63, f = (i >> 9) & 7, ks = i >> 12;
    int k = ks * 32 + ((l >> 4) << 3) + j;
    int n = f * 16 + (l & 15);
    int h_ = k >> 7, ko = k & 127;
    wpsz[i] = f2b(W_last[(size_t)ko * 1024 + h_ * 128 + n] * 0.125f);
  }
  if (i < 2048) {  // wlr fragment build
    int j = i & 7, l = (i >> 3) & 63, ks = i >> 9;
    int k = ks * 32 + ((l >> 4) << 3) + j;
    int n = l & 15;
    int hh = n & 7;
    const float* av = (n < 8) ? (al_last + hh * 128) : (ar_last + hh * 128);
    float s = 0.f;
    for (int d = 0; d < 128; ++d) s += W_last[(size_t)k * 1024 + hh * 128 + d] * av[d];
    wlrsz[i] = f2b(s);
  }
  if (i < 128) {
    float s = 0.f;
#pragma unroll
    for (int hh = 0; hh < 8; ++hh) s += b_last[hh * 128 + i];
    mb[i] = s * 0.125f;
  }
}

// ---------------- degree count + last-block prefix scan ----------------
// Ticket acquire (ACQ_REL, agent scope) invalidates L1 -> plain loads below are coherent.
__global__ __launch_bounds__(256) void count_scan(const int* __restrict__ dst,
                                                  int* __restrict__ deg,
                                                  int* __restrict__ off,
                                                  int* __restrict__ cursor,
                                                  int* __restrict__ ticket) {
  int e = blockIdx.x * 256 + threadIdx.x;
  if (e < N_EDGES) atomicAdd(&deg[dst[e]], 1);
  __threadfence();
  __syncthreads();  // all waves of this block finish their adds before ticket
  __shared__ int lastFlag;
  if (threadIdx.x == 0) {
    int t = __hip_atomic_fetch_add(ticket, 1, __ATOMIC_ACQ_REL, __HIP_MEMORY_SCOPE_AGENT);
    lastFlag = (t == (int)gridDim.x - 1);
  }
  __syncthreads();
  if (!lastFlag) return;

  // last block: exclusive scan with plain pipelined loads (post-acquire, L1 invalidated)
  __shared__ int part[256];
  const int tid = threadIdx.x;
  const int NPT = (N_NODES + 255) / 256;  // 79
  const int b0 = tid * NPT, b1 = min(N_NODES, b0 + NPT);
  int s = 0;
  {
    int j = b0;
    for (; j + 4 <= b1; j += 4) {
      int d0 = deg[j], d1 = deg[j + 1], d2 = deg[j + 2], d3 = deg[j + 3];
      s += d0 + d1 + d2 + d3;
    }
    for (; j < b1; ++j) s += deg[j];
  }
  part[tid] = s;
  __syncthreads();
  for (int ofs = 1; ofs < 256; ofs <<= 1) {
    int v = (tid >= ofs) ? part[tid - ofs] : 0;
    __syncthreads();
    part[tid] += v;
    __syncthreads();
  }
  int run = (tid > 0) ? part[tid - 1] : 0;
  {
    int j = b0;
    for (; j + 4 <= b1; j += 4) {
      int d0 = deg[j], d1 = deg[j + 1], d2 = deg[j + 2], d3 = deg[j + 3];
      off[j] = run; cursor[j] = run; run += d0;
      off[j + 1] = run; cursor[j + 1] = run; run += d1;
      off[j + 2] = run; cursor[j + 2] = run; run += d2;
      off[j + 3] = run; cursor[j + 3] = run; run += d3;
    }
    for (; j < b1; ++j) {
      off[j] = run; cursor[j] = run; run += deg[j];
    }
  }
  if (tid == 255) off[N_NODES] = part[255];
}

// ---------------- MFMA GEMM device body ----------------
template <int K, bool LAST>
__device__ __forceinline__ void dev_gemm(int tile, const unsigned short* __restrict__ A,
                                         const unsigned short* __restrict__ Bsz,
                                         const float* __restrict__ hres,
                                         const float* __restrict__ mbv,
                                         unsigned short* __restrict__ Cb,
                                         float* __restrict__ Cf,
                                         const float* __restrict__ al,
                                         const float* __restrict__ ar,
                                         float* __restrict__ elr, int lane, int wid) {
  const int wrow = wid & 1, wc = wid >> 1;
  const int r0 = tile * 32;
  const int arow = r0 + wrow * 16 + (lane & 15);
  const int kg = lane >> 4;

  f32x4 acc[4];
#pragma unroll
  for (int fi = 0; fi < 4; ++fi) acc[fi] = {0.f, 0.f, 0.f, 0.f};

  const bf16x8* Ap = (const bf16x8*)(A + (size_t)arow * K + kg * 8);
#pragma unroll 4
  for (int ks = 0; ks < K / 32; ++ks) {
    bf16x8 a = Ap[ks * 4];
#pragma unroll
    for (int fi = 0; fi < 4; ++fi) {
      int f = wc * 4 + fi;
      bf16x8 b = *(const bf16x8*)(Bsz + (((size_t)(ks * 8 + f) * 64 + lane) << 3));
      acc[fi] = __builtin_amdgcn_mfma_f32_16x16x32_bf16(a, b, acc[fi], 0, 0, 0);
    }
  }

  const int rbase = r0 + wrow * 16 + (lane >> 4) * 4;
#pragma unroll
  for (int fi = 0; fi < 4; ++fi) {
    int col = wc * 64 + fi * 16 + (lane & 15);
#pragma unroll
    for (int r = 0; r < 4; ++r) {
      int row = rbase + r;
      float v = acc[fi][r];
      if (LAST)
        Cf[(size_t)row * DM + col] = v + hres[(size_t)row * DM + col] + mbv[col];
      else
        Cb[(size_t)row * DM + col] = f2b(v);
    }
  }

  if (!LAST) {
#pragma unroll
    for (int fi = 0; fi < 4; ++fi) {
      int hh = wc * 4 + fi;
      float alv = al[hh * 16 + (lane & 15)];
      float arv = ar[hh * 16 + (lane & 15)];
#pragma unroll
      for (int r = 0; r < 4; ++r) {
        float pl = acc[fi][r] * alv;
        float pr = acc[fi][r] * arv;
#pragma unroll
        for (int msk = 1; msk < 16; msk <<= 1) {
          pl += __shfl_xor(pl, msk, 64);
          pr += __shfl_xor(pr, msk, 64);
        }
        if ((lane & 15) == 0) {
          int row = rbase + r;
          elr[row * 16 + hh] = pl;
          elr[row * 16 + 8 + hh] = pr;
        }
      }
    }
  }
}

// layer0 GEMM || CSR scatter (independent outputs, both consumed by fused0)
__global__ __launch_bounds__(256) void gemm0_scatter(
    const unsigned short* __restrict__ A, const unsigned short* __restrict__ Bsz,
    unsigned short* __restrict__ Cb, const float* __restrict__ al,
    const float* __restrict__ ar, float* __restrict__ elr, const int* __restrict__ srcE,
    const int* __restrict__ dstE, int* __restrict__ cursor, int* __restrict__ csr_src) {
  const int bid = blockIdx.x;
  if (bid < N_NODES / 32) {
    dev_gemm<DM, false>(bid, A, Bsz, nullptr, nullptr, Cb, nullptr, al, ar, elr,
                        threadIdx.x & 63, threadIdx.x >> 6);
  } else {
    int e = (bid - N_NODES / 32) * 256 + threadIdx.x;
    if (e < N_EDGES) {
      int pos = atomicAdd(&cursor[dstE[e]], 1);
      csr_src[pos] = srcE[e];
    }
  }
}

template <int K, bool LAST>
__global__ __launch_bounds__(256) void gemm_mfma(
    const unsigned short* __restrict__ A, const unsigned short* __restrict__ Bsz,
    const float* __restrict__ hres, const float* __restrict__ mbv,
    unsigned short* __restrict__ Cb, float* __restrict__ Cf,
    const float* __restrict__ al, const float* __restrict__ ar, float* __restrict__ elr) {
  dev_gemm<K, LAST>(blockIdx.x, A, Bsz, hres, mbv, Cb, Cf, al, ar, elr, threadIdx.x & 63,
                    threadIdx.x >> 6);
}

// ---------------- layers 0/1: fused softmax+agg (+optional elr_last epilogue) ----------------
// ELR epilogue writes to elr_out (a SEPARATE buffer from the elr being read).
template <bool ELR>
__global__ __launch_bounds__(256) void fused_small(
    const int* __restrict__ off, const int* __restrict__ csr_src,
    const unsigned short* __restrict__ feat, const float* __restrict__ elr,
    const float* __restrict__ bias, float* __restrict__ h, unsigned short* __restrict__ hb,
    const unsigned short* __restrict__ wlrsz, float* __restrict__ elr_out) {
  __shared__ float a_lds[4][64];
  __shared__ int s_lds[4][8];
  __shared__ float zi_lds[4][8];
  __shared__ __align__(16) unsigned short nh_lds[4][128];
  const int wid = threadIdx.x >> 6;
  const int t = blockIdx.x * 4 + wid;
  const int lane = threadIdx.x & 63;
  const int e_loc = lane >> 3, hh = lane & 7;
  const int hg = lane >> 3;  // head for dims 2*lane, 2*lane+1
  const int beg = off[t], end = off[t + 1];
  const float ert = elr[t * 16 + 8 + hh];

  int e = beg + e_loc;
  bool val = e < end;
  int s = val ? csr_src[e] : 0;
  float xl = val ? elr[s * 16 + hh] : 0.f;

  float z = 0.f, acc0 = 0.f, acc1 = 0.f;
  for (int base = beg; base < end; base += 8) {
    float ex = 0.f;
    if (val) {
      float xv = xl + ert;
      xv = xv > 0.f ? xv : 0.2f * xv;
      ex = __expf(xv);
    }
    a_lds[wid][lane] = ex;
    if (hh == 0) s_lds[wid][e_loc] = s;
    __builtin_amdgcn_wave_barrier();
    asm volatile("s_waitcnt lgkmcnt(0)" ::: "memory");
    z += ex;
    int en = base + 8 + e_loc;
    bool valn = en < end;
    int sn = valn ? csr_src[en] : 0;
    float xln = valn ? elr[sn * 16 + hh] : 0.f;
    int n = min(8, end - base);
    for (int e2 = 0; e2 < n; ++e2) {
      int s2 = s_lds[wid][e2];
      float a = a_lds[wid][e2 * 8 + hg];
      unsigned int hv = *(const unsigned int*)&feat[(size_t)s2 * 128 + 2 * lane];
      acc0 += a * b2f((unsigned short)(hv & 0xffffu));
      acc1 += a * b2f((unsigned short)(hv >> 16));
    }
    __builtin_amdgcn_wave_barrier();
    s = sn;
    xl = xln;
    val = valn;
  }
  z += __shfl_xor(z, 8, 64);
  z += __shfl_xor(z, 16, 64);
  z += __shfl_xor(z, 32, 64);
  if (e_loc == 0) zi_lds[wid][hh] = (z > 0.f) ? 1.f / z : 0.f;
  __builtin_amdgcn_wave_barrier();
  asm volatile("s_waitcnt lgkmcnt(0)" ::: "memory");
  float zi = zi_lds[wid][hg];

  float2 bv = *(const float2*)&bias[2 * lane];
  float v0 = acc0 * zi + bv.x;
  float v1 = acc1 * zi + bv.y;
  v0 = v0 > 0.f ? v0 : expm1f(v0);
  v1 = v1 > 0.f ? v1 : expm1f(v1);
  size_t idx = (size_t)t * 128 + 2 * lane;
  float2 hv = *(const float2*)&h[idx];
  float nh0 = hv.x + v0;
  float nh1 = hv.y + v1;
  *(float2*)&h[idx] = make_float2(nh0, nh1);
  unsigned short b0 = f2b(nh0), b1 = f2b(nh1);
  *(ushort2*)&hb[idx] = make_ushort2(b0, b1);

  if (ELR) {
    // elr_last fused: elr_out[t][0..15] = nh @ [wl|wr] via one MFMA chain
    *(ushort2*)&nh_lds[wid][2 * lane] = make_ushort2(b0, b1);
    __builtin_amdgcn_wave_barrier();
    asm volatile("s_waitcnt lgkmcnt(0)" ::: "memory");
    const int kg = lane >> 4;
    f32x4 acc = {0.f, 0.f, 0.f, 0.f};
#pragma unroll
    for (int ks = 0; ks < 4; ++ks) {
      bf16x8 a = *(const bf16x8*)&nh_lds[wid][ks * 32 + kg * 8];
      bf16x8 b = *(const bf16x8*)(wlrsz + (((size_t)ks * 64 + lane) << 3));
      acc = __builtin_amdgcn_mfma_f32_16x16x32_bf16(a, b, acc, 0, 0, 0);
    }
    if (lane < 16) elr_out[t * 16 + lane] = acc[0];
  }
}

// ---------------- last layer: fused softmax+agg, single pass, pipelined ----------------
__global__ __launch_bounds__(256) void fused_last(
    const int* __restrict__ off, const int* __restrict__ csr_src,
    const unsigned short* __restrict__ hb, const float* __restrict__ elr,
    unsigned short* __restrict__ g) {
  __shared__ float a_lds[4][64];
  __shared__ int s_lds[4][8];
  __shared__ float zi_lds[4][8];
  const int wid = threadIdx.x >> 6;
  const int t = blockIdx.x * 4 + wid;
  const int lane = threadIdx.x & 63;
  const int e_loc = lane >> 3, hh = lane & 7;
  const int beg = off[t], end = off[t + 1];
  const float ert = elr[t * 16 + 8 + hh];

  int e = beg + e_loc;
  bool val = e < end;
  int s = val ? csr_src[e] : 0;
  float xl = val ? elr[s * 16 + hh] : 0.f;

  float z = 0.f;
  float accA[8], accB[8];
#pragma unroll
  for (int k = 0; k < 8; ++k) accA[k] = accB[k] = 0.f;

  for (int base = beg; base < end; base += 8) {
    float ex = 0.f;
    if (val) {
      float xv = xl + ert;
      xv = xv > 0.f ? xv : 0.2f * xv;
      ex = __expf(xv);
    }
    a_lds[wid][lane] = ex;
    if (hh == 0) s_lds[wid][e_loc] = s;
    __builtin_amdgcn_wave_barrier();
    asm volatile("s_waitcnt lgkmcnt(0)" ::: "memory");
    z += ex;
    int en = base + 8 + e_loc;
    bool valn = en < end;
    int sn = valn ? csr_src[en] : 0;
    float xln = valn ? elr[sn * 16 + hh] : 0.f;
    int n = min(8, end - base);
    for (int e2 = 0; e2 < n; ++e2) {
      int s2 = s_lds[wid][e2];
      float4 pa = *(const float4*)&a_lds[wid][e2 * 8];
      float4 pb = *(const float4*)&a_lds[wid][e2 * 8 + 4];
      unsigned int hv = *(const unsigned int*)&hb[(size_t)s2 * 128 + 2 * lane];
      float h0 = b2f((unsigned short)(hv & 0xffffu));
      float h1 = b2f((unsigned short)(hv >> 16));
      accA[0] += pa.x * h0; accB[0] += pa.x * h1;
      accA[1] += pa.y * h0; accB[1] += pa.y * h1;
      accA[2] += pa.z * h0; accB[2] += pa.z * h1;
      accA[3] += pa.w * h0; accB[3] += pa.w * h1;
      accA[4] += pb.x * h0; accB[4] += pb.x * h1;
      accA[5] += pb.y * h0; accB[5] += pb.y * h1;
      accA[6] += pb.z * h0; accB[6] += pb.z * h1;
      accA[7] += pb.w * h0; accB[7] += pb.w * h1;
    }
    __builtin_amdgcn_wave_barrier();
    s = sn;
    xl = xln;
    val = valn;
  }
  z += __shfl_xor(z, 8, 64);
  z += __shfl_xor(z, 16, 64);
  z += __shfl_xor(z, 32, 64);
  if (e_loc == 0) zi_lds[wid][hh] = (z > 0.f) ? 1.f / z : 0.f;
  __builtin_amdgcn_wave_barrier();
  asm volatile("s_waitcnt lgkmcnt(0)" ::: "memory");
  float4 zia = *(const float4*)&zi_lds[wid][0];
  float4 zib = *(const float4*)&zi_lds[wid][4];
  float ziv[8] = {zia.x, zia.y, zia.z, zia.w, zib.x, zib.y, zib.z, zib.w};
#pragma unroll
  for (int h2 = 0; h2 < 8; ++h2) {
    *(ushort2*)&g[(size_t)t * 1024 + h2 * 128 + 2 * lane] =
        make_ushort2(f2b(accA[h2] * ziv[h2]), f2b(accB[h2] * ziv[h2]));
  }
}

extern "C" void kernel_launch(void* const* d_in, const int* in_sizes, int n_in,
                              void* d_out, int out_size, void* d_ws, size_t ws_size,
                              hipStream_t stream) {
  const float* x = (const float*)d_in[0];
  const int* src = (const int*)d_in[1];
  const int* dst = (const int*)d_in[2];
  const float* Ws = (const float*)d_in[3];
  const float* als = (const float*)d_in[4];
  const float* ars = (const float*)d_in[5];
  const float* bs = (const float*)d_in[6];
  const float* W_last = (const float*)d_in[7];
  const float* al_last = (const float*)d_in[8];
  const float* ar_last = (const float*)d_in[9];
  const float* b_last = (const float*)d_in[10];
  float* out = (float*)d_out;

  // ---- workspace layout ----
  float* h = (float*)d_ws;                           // 2,560,000 f
  float* elr = h + 2560000;                          // 320,000 f
  float* elr2 = elr + 320000;                        // 320,000 f (last-layer scores)
  float* mb = elr2 + 320000;                         // 128 f
  unsigned short* hb = (unsigned short*)(mb + 128);  // 2,560,000 us
  unsigned short* feat = hb + 2560000;               // 2,560,000 us
  unsigned short* g = feat + 2560000;                // 20,480,000 us
  unsigned short* wsz = g + 20480000;                // 32,768 us
  unsigned short* wpsz = wsz + 32768;                // 131,072 us
  unsigned short* wlrsz = wpsz + 131072;             // 2,048 us
  int* deg = (int*)(wlrsz + 2048);
  int* off = deg + N_NODES;
  int* cursor = off + N_NODES + 1;
  int* csr_src = cursor + N_NODES;
  int* ticket = csr_src + N_EDGES;

  const int GB = N_NODES / 32;            // 625
  const int FB = N_NODES / 4;             // 5000
  const int EB = (N_EDGES + 255) / 256;   // 782

  prep_all<<<(N_NODES * DM / 4 + 255) / 256, 256, 0, stream>>>(
      x, h, hb, Ws, wsz, W_last, wpsz, al_last, ar_last, b_last, wlrsz, mb, deg, ticket);
  count_scan<<<EB, 256, 0, stream>>>(dst, deg, off, cursor, ticket);
  gemm0_scatter<<<GB + EB, 256, 0, stream>>>(hb, wsz, feat, als, ars, elr, src, dst,
                                             cursor, csr_src);
  fused_small<false><<<FB, 256, 0, stream>>>(off, csr_src, feat, elr, bs, h, hb, nullptr,
                                             nullptr);
  gemm_mfma<DM, false><<<GB, 256, 0, stream>>>(hb, wsz + 16384, nullptr, nullptr, feat,
                                               nullptr, als + 128, ars + 128, elr);
  fused_small<true><<<FB, 256, 0, stream>>>(off, csr_src, feat, elr, bs + 128, h, hb,
                                            wlrsz, elr2);
  fused_last<<<FB, 256, 0, stream>>>(off, csr_src, hb, elr2, g);
  gemm_mfma<NH * DM, true><<<GB, 256, 0, stream>>>(g, wpsz, h, mb, nullptr, out, nullptr,
                                                   nullptr, nullptr);
}

// Round 14
// 192.041 us; speedup vs baseline: 4.2702x; 1.1401x over previous
//
#include <hip/hip_runtime.h>
#include <math.h>

#define N_NODES 20000
#define N_EDGES 200000
#define DM 128
#define NH 8

typedef __attribute__((ext_vector_type(8))) short bf16x8;
typedef __attribute__((ext_vector_type(4))) float f32x4;

__device__ __forceinline__ unsigned short f2b(float f) {
  unsigned int u = __float_as_uint(f);
  unsigned int r = (u + 0x7FFFu + ((u >> 16) & 1u)) >> 16;  // RNE
  return (unsigned short)r;
}
__device__ __forceinline__ float b2f(unsigned short s) {
  return __uint_as_float(((unsigned int)s) << 16);
}

// ---------------- prep: cast + deg zero + all weight prep ----------------
__global__ __launch_bounds__(256) void prep_all(
    const float* __restrict__ x, float* __restrict__ h, unsigned short* __restrict__ hb,
    const float* __restrict__ Ws, unsigned short* __restrict__ wsz,
    const float* __restrict__ W_last, unsigned short* __restrict__ wpsz,
    const float* __restrict__ al_last, const float* __restrict__ ar_last,
    const float* __restrict__ b_last, unsigned short* __restrict__ wlrsz,
    float* __restrict__ mb, int* __restrict__ deg) {
  int i = blockIdx.x * 256 + threadIdx.x;
  if (i < (N_NODES * DM) / 4) {  // float4 cast
    float4 v = ((const float4*)x)[i];
    ((float4*)h)[i] = v;
    ((ushort4*)hb)[i] = make_ushort4(f2b(v.x), f2b(v.y), f2b(v.z), f2b(v.w));
  }
  if (i < N_NODES) deg[i] = 0;
  if (i < 2 * 16384) {  // layers 0/1 B swizzle
    int layer = i >> 14;
    int r = i & 16383;
    int j = r & 7, l = (r >> 3) & 63, f = (r >> 9) & 7, ks = r >> 12;
    int k = ks * 32 + ((l >> 4) << 3) + j;
    int n = f * 16 + (l & 15);
    wsz[i] = f2b(Ws[(size_t)layer * 16384 + k * 128 + n]);
  }
  if (i < 131072) {  // last-layer B swizzle (1/8 mean folded)
    int j = i & 7, l = (i >> 3) & 63, f = (i >> 9) & 7, ks = i >> 12;
    int k = ks * 32 + ((l >> 4) << 3) + j;
    int n = f * 16 + (l & 15);
    int h_ = k >> 7, ko = k & 127;
    wpsz[i] = f2b(W_last[(size_t)ko * 1024 + h_ * 128 + n] * 0.125f);
  }
  if (i < 2048) {  // wlr fragment build
    int j = i & 7, l = (i >> 3) & 63, ks = i >> 9;
    int k = ks * 32 + ((l >> 4) << 3) + j;
    int n = l & 15;
    int hh = n & 7;
    const float* av = (n < 8) ? (al_last + hh * 128) : (ar_last + hh * 128);
    float s = 0.f;
    for (int d = 0; d < 128; ++d) s += W_last[(size_t)k * 1024 + hh * 128 + d] * av[d];
    wlrsz[i] = f2b(s);
  }
  if (i < 128) {
    float s = 0.f;
#pragma unroll
    for (int hh = 0; hh < 8; ++hh) s += b_last[hh * 128 + i];
    mb[i] = s * 0.125f;
  }
}

// ---------------- degree count (kernel boundary = coherence barrier) ----------------
__global__ __launch_bounds__(256) void count_deg(const int* __restrict__ dst,
                                                 int* __restrict__ deg) {
  int e = blockIdx.x * 256 + threadIdx.x;
  if (e < N_EDGES) atomicAdd(&deg[dst[e]], 1);
}

// ---------------- single-block exclusive scan (R1-R7 proven version) ----------------
__global__ void scan_deg(const int* __restrict__ deg, int* __restrict__ off,
                         int* __restrict__ cursor) {
  __shared__ int part[1024];
  const int tid = threadIdx.x;
  const int CHUNK = (N_NODES + 1023) / 1024;  // 20
  int base = tid * CHUNK;
  int s = 0;
  for (int i = 0; i < CHUNK; ++i) {
    int idx = base + i;
    if (idx < N_NODES) s += deg[idx];
  }
  part[tid] = s;
  __syncthreads();
  for (int ofs = 1; ofs < 1024; ofs <<= 1) {
    int v = (tid >= ofs) ? part[tid - ofs] : 0;
    __syncthreads();
    part[tid] += v;
    __syncthreads();
  }
  int run = (tid > 0) ? part[tid - 1] : 0;
  for (int i = 0; i < CHUNK; ++i) {
    int idx = base + i;
    if (idx < N_NODES) {
      off[idx] = run;
      cursor[idx] = run;
      run += deg[idx];
    }
  }
  if (tid == 0) off[N_NODES] = part[1023];
}

// ---------------- MFMA GEMM device body ----------------
template <int K, bool LAST>
__device__ __forceinline__ void dev_gemm(int tile, const unsigned short* __restrict__ A,
                                         const unsigned short* __restrict__ Bsz,
                                         const float* __restrict__ hres,
                                         const float* __restrict__ mbv,
                                         unsigned short* __restrict__ Cb,
                                         float* __restrict__ Cf,
                                         const float* __restrict__ al,
                                         const float* __restrict__ ar,
                                         float* __restrict__ elr, int lane, int wid) {
  const int wrow = wid & 1, wc = wid >> 1;
  const int r0 = tile * 32;
  const int arow = r0 + wrow * 16 + (lane & 15);
  const int kg = lane >> 4;

  f32x4 acc[4];
#pragma unroll
  for (int fi = 0; fi < 4; ++fi) acc[fi] = {0.f, 0.f, 0.f, 0.f};

  const bf16x8* Ap = (const bf16x8*)(A + (size_t)arow * K + kg * 8);
#pragma unroll 4
  for (int ks = 0; ks < K / 32; ++ks) {
    bf16x8 a = Ap[ks * 4];
#pragma unroll
    for (int fi = 0; fi < 4; ++fi) {
      int f = wc * 4 + fi;
      bf16x8 b = *(const bf16x8*)(Bsz + (((size_t)(ks * 8 + f) * 64 + lane) << 3));
      acc[fi] = __builtin_amdgcn_mfma_f32_16x16x32_bf16(a, b, acc[fi], 0, 0, 0);
    }
  }

  const int rbase = r0 + wrow * 16 + (lane >> 4) * 4;
#pragma unroll
  for (int fi = 0; fi < 4; ++fi) {
    int col = wc * 64 + fi * 16 + (lane & 15);
#pragma unroll
    for (int r = 0; r < 4; ++r) {
      int row = rbase + r;
      float v = acc[fi][r];
      if (LAST)
        Cf[(size_t)row * DM + col] = v + hres[(size_t)row * DM + col] + mbv[col];
      else
        Cb[(size_t)row * DM + col] = f2b(v);
    }
  }

  if (!LAST) {
#pragma unroll
    for (int fi = 0; fi < 4; ++fi) {
      int hh = wc * 4 + fi;
      float alv = al[hh * 16 + (lane & 15)];
      float arv = ar[hh * 16 + (lane & 15)];
#pragma unroll
      for (int r = 0; r < 4; ++r) {
        float pl = acc[fi][r] * alv;
        float pr = acc[fi][r] * arv;
#pragma unroll
        for (int msk = 1; msk < 16; msk <<= 1) {
          pl += __shfl_xor(pl, msk, 64);
          pr += __shfl_xor(pr, msk, 64);
        }
        if ((lane & 15) == 0) {
          int row = rbase + r;
          elr[row * 16 + hh] = pl;
          elr[row * 16 + 8 + hh] = pr;
        }
      }
    }
  }
}

// layer0 GEMM || CSR scatter (independent outputs, both consumed by fused0)
__global__ __launch_bounds__(256) void gemm0_scatter(
    const unsigned short* __restrict__ A, const unsigned short* __restrict__ Bsz,
    unsigned short* __restrict__ Cb, const float* __restrict__ al,
    const float* __restrict__ ar, float* __restrict__ elr, const int* __restrict__ srcE,
    const int* __restrict__ dstE, int* __restrict__ cursor, int* __restrict__ csr_src) {
  const int bid = blockIdx.x;
  if (bid < N_NODES / 32) {
    dev_gemm<DM, false>(bid, A, Bsz, nullptr, nullptr, Cb, nullptr, al, ar, elr,
                        threadIdx.x & 63, threadIdx.x >> 6);
  } else {
    int e = (bid - N_NODES / 32) * 256 + threadIdx.x;
    if (e < N_EDGES) {
      int pos = atomicAdd(&cursor[dstE[e]], 1);
      csr_src[pos] = srcE[e];
    }
  }
}

template <int K, bool LAST>
__global__ __launch_bounds__(256) void gemm_mfma(
    const unsigned short* __restrict__ A, const unsigned short* __restrict__ Bsz,
    const float* __restrict__ hres, const float* __restrict__ mbv,
    unsigned short* __restrict__ Cb, float* __restrict__ Cf,
    const float* __restrict__ al, const float* __restrict__ ar, float* __restrict__ elr) {
  dev_gemm<K, LAST>(blockIdx.x, A, Bsz, hres, mbv, Cb, Cf, al, ar, elr, threadIdx.x & 63,
                    threadIdx.x >> 6);
}

// ---------------- layers 0/1: fused softmax+agg (+optional elr_last epilogue) ----------------
// ELR epilogue writes to elr_out (a SEPARATE buffer from the elr being read).
template <bool ELR>
__global__ __launch_bounds__(256) void fused_small(
    const int* __restrict__ off, const int* __restrict__ csr_src,
    const unsigned short* __restrict__ feat, const float* __restrict__ elr,
    const float* __restrict__ bias, float* __restrict__ h, unsigned short* __restrict__ hb,
    const unsigned short* __restrict__ wlrsz, float* __restrict__ elr_out) {
  __shared__ float a_lds[4][64];
  __shared__ int s_lds[4][8];
  __shared__ float zi_lds[4][8];
  __shared__ __align__(16) unsigned short nh_lds[4][128];
  const int wid = threadIdx.x >> 6;
  const int t = blockIdx.x * 4 + wid;
  const int lane = threadIdx.x & 63;
  const int e_loc = lane >> 3, hh = lane & 7;
  const int hg = lane >> 3;  // head for dims 2*lane, 2*lane+1
  const int beg = off[t], end = off[t + 1];
  const float ert = elr[t * 16 + 8 + hh];

  int e = beg + e_loc;
  bool val = e < end;
  int s = val ? csr_src[e] : 0;
  float xl = val ? elr[s * 16 + hh] : 0.f;

  float z = 0.f, acc0 = 0.f, acc1 = 0.f;
  for (int base = beg; base < end; base += 8) {
    float ex = 0.f;
    if (val) {
      float xv = xl + ert;
      xv = xv > 0.f ? xv : 0.2f * xv;
      ex = __expf(xv);
    }
    a_lds[wid][lane] = ex;
    if (hh == 0) s_lds[wid][e_loc] = s;
    __builtin_amdgcn_wave_barrier();
    asm volatile("s_waitcnt lgkmcnt(0)" ::: "memory");
    z += ex;
    int en = base + 8 + e_loc;
    bool valn = en < end;
    int sn = valn ? csr_src[en] : 0;
    float xln = valn ? elr[sn * 16 + hh] : 0.f;
    int n = min(8, end - base);
    for (int e2 = 0; e2 < n; ++e2) {
      int s2 = s_lds[wid][e2];
      float a = a_lds[wid][e2 * 8 + hg];
      unsigned int hv = *(const unsigned int*)&feat[(size_t)s2 * 128 + 2 * lane];
      acc0 += a * b2f((unsigned short)(hv & 0xffffu));
      acc1 += a * b2f((unsigned short)(hv >> 16));
    }
    __builtin_amdgcn_wave_barrier();
    s = sn;
    xl = xln;
    val = valn;
  }
  z += __shfl_xor(z, 8, 64);
  z += __shfl_xor(z, 16, 64);
  z += __shfl_xor(z, 32, 64);
  if (e_loc == 0) zi_lds[wid][hh] = (z > 0.f) ? 1.f / z : 0.f;
  __builtin_amdgcn_wave_barrier();
  asm volatile("s_waitcnt lgkmcnt(0)" ::: "memory");
  float zi = zi_lds[wid][hg];

  float2 bv = *(const float2*)&bias[2 * lane];
  float v0 = acc0 * zi + bv.x;
  float v1 = acc1 * zi + bv.y;
  v0 = v0 > 0.f ? v0 : expm1f(v0);
  v1 = v1 > 0.f ? v1 : expm1f(v1);
  size_t idx = (size_t)t * 128 + 2 * lane;
  float2 hv = *(const float2*)&h[idx];
  float nh0 = hv.x + v0;
  float nh1 = hv.y + v1;
  *(float2*)&h[idx] = make_float2(nh0, nh1);
  unsigned short b0 = f2b(nh0), b1 = f2b(nh1);
  *(ushort2*)&hb[idx] = make_ushort2(b0, b1);

  if (ELR) {
    // elr_last fused: elr_out[t][0..15] = nh @ [wl|wr] via one MFMA chain
    *(ushort2*)&nh_lds[wid][2 * lane] = make_ushort2(b0, b1);
    __builtin_amdgcn_wave_barrier();
    asm volatile("s_waitcnt lgkmcnt(0)" ::: "memory");
    const int kg = lane >> 4;
    f32x4 acc = {0.f, 0.f, 0.f, 0.f};
#pragma unroll
    for (int ks = 0; ks < 4; ++ks) {
      bf16x8 a = *(const bf16x8*)&nh_lds[wid][ks * 32 + kg * 8];
      bf16x8 b = *(const bf16x8*)(wlrsz + (((size_t)ks * 64 + lane) << 3));
      acc = __builtin_amdgcn_mfma_f32_16x16x32_bf16(a, b, acc, 0, 0, 0);
    }
    if (lane < 16) elr_out[t * 16 + lane] = acc[0];
  }
}

// ---------------- last layer: fused softmax+agg, single pass, pipelined ----------------
__global__ __launch_bounds__(256) void fused_last(
    const int* __restrict__ off, const int* __restrict__ csr_src,
    const unsigned short* __restrict__ hb, const float* __restrict__ elr,
    unsigned short* __restrict__ g) {
  __shared__ float a_lds[4][64];
  __shared__ int s_lds[4][8];
  __shared__ float zi_lds[4][8];
  const int wid = threadIdx.x >> 6;
  const int t = blockIdx.x * 4 + wid;
  const int lane = threadIdx.x & 63;
  const int e_loc = lane >> 3, hh = lane & 7;
  const int beg = off[t], end = off[t + 1];
  const float ert = elr[t * 16 + 8 + hh];

  int e = beg + e_loc;
  bool val = e < end;
  int s = val ? csr_src[e] : 0;
  float xl = val ? elr[s * 16 + hh] : 0.f;

  float z = 0.f;
  float accA[8], accB[8];
#pragma unroll
  for (int k = 0; k < 8; ++k) accA[k] = accB[k] = 0.f;

  for (int base = beg; base < end; base += 8) {
    float ex = 0.f;
    if (val) {
      float xv = xl + ert;
      xv = xv > 0.f ? xv : 0.2f * xv;
      ex = __expf(xv);
    }
    a_lds[wid][lane] = ex;
    if (hh == 0) s_lds[wid][e_loc] = s;
    __builtin_amdgcn_wave_barrier();
    asm volatile("s_waitcnt lgkmcnt(0)" ::: "memory");
    z += ex;
    int en = base + 8 + e_loc;
    bool valn = en < end;
    int sn = valn ? csr_src[en] : 0;
    float xln = valn ? elr[sn * 16 + hh] : 0.f;
    int n = min(8, end - base);
    for (int e2 = 0; e2 < n; ++e2) {
      int s2 = s_lds[wid][e2];
      float4 pa = *(const float4*)&a_lds[wid][e2 * 8];
      float4 pb = *(const float4*)&a_lds[wid][e2 * 8 + 4];
      unsigned int hv = *(const unsigned int*)&hb[(size_t)s2 * 128 + 2 * lane];
      float h0 = b2f((unsigned short)(hv & 0xffffu));
      float h1 = b2f((unsigned short)(hv >> 16));
      accA[0] += pa.x * h0; accB[0] += pa.x * h1;
      accA[1] += pa.y * h0; accB[1] += pa.y * h1;
      accA[2] += pa.z * h0; accB[2] += pa.z * h1;
      accA[3] += pa.w * h0; accB[3] += pa.w * h1;
      accA[4] += pb.x * h0; accB[4] += pb.x * h1;
      accA[5] += pb.y * h0; accB[5] += pb.y * h1;
      accA[6] += pb.z * h0; accB[6] += pb.z * h1;
      accA[7] += pb.w * h0; accB[7] += pb.w * h1;
    }
    __builtin_amdgcn_wave_barrier();
    s = sn;
    xl = xln;
    val = valn;
  }
  z += __shfl_xor(z, 8, 64);
  z += __shfl_xor(z, 16, 64);
  z += __shfl_xor(z, 32, 64);
  if (e_loc == 0) zi_lds[wid][hh] = (z > 0.f) ? 1.f / z : 0.f;
  __builtin_amdgcn_wave_barrier();
  asm volatile("s_waitcnt lgkmcnt(0)" ::: "memory");
  float4 zia = *(const float4*)&zi_lds[wid][0];
  float4 zib = *(const float4*)&zi_lds[wid][4];
  float ziv[8] = {zia.x, zia.y, zia.z, zia.w, zib.x, zib.y, zib.z, zib.w};
#pragma unroll
  for (int h2 = 0; h2 < 8; ++h2) {
    *(ushort2*)&g[(size_t)t * 1024 + h2 * 128 + 2 * lane] =
        make_ushort2(f2b(accA[h2] * ziv[h2]), f2b(accB[h2] * ziv[h2]));
  }
}

extern "C" void kernel_launch(void* const* d_in, const int* in_sizes, int n_in,
                              void* d_out, int out_size, void* d_ws, size_t ws_size,
                              hipStream_t stream) {
  const float* x = (const float*)d_in[0];
  const int* src = (const int*)d_in[1];
  const int* dst = (const int*)d_in[2];
  const float* Ws = (const float*)d_in[3];
  const float* als = (const float*)d_in[4];
  const float* ars = (const float*)d_in[5];
  const float* bs = (const float*)d_in[6];
  const float* W_last = (const float*)d_in[7];
  const float* al_last = (const float*)d_in[8];
  const float* ar_last = (const float*)d_in[9];
  const float* b_last = (const float*)d_in[10];
  float* out = (float*)d_out;

  // ---- workspace layout ----
  float* h = (float*)d_ws;                           // 2,560,000 f
  float* elr = h + 2560000;                          // 320,000 f
  float* elr2 = elr + 320000;                        // 320,000 f (last-layer scores)
  float* mb = elr2 + 320000;                         // 128 f
  unsigned short* hb = (unsigned short*)(mb + 128);  // 2,560,000 us
  unsigned short* feat = hb + 2560000;               // 2,560,000 us
  unsigned short* g = feat + 2560000;                // 20,480,000 us
  unsigned short* wsz = g + 20480000;                // 32,768 us
  unsigned short* wpsz = wsz + 32768;                // 131,072 us
  unsigned short* wlrsz = wpsz + 131072;             // 2,048 us
  int* deg = (int*)(wlrsz + 2048);
  int* off = deg + N_NODES;
  int* cursor = off + N_NODES + 1;
  int* csr_src = cursor + N_NODES;

  const int GB = N_NODES / 32;            // 625
  const int FB = N_NODES / 4;             // 5000
  const int EB = (N_EDGES + 255) / 256;   // 782

  prep_all<<<(N_NODES * DM / 4 + 255) / 256, 256, 0, stream>>>(
      x, h, hb, Ws, wsz, W_last, wpsz, al_last, ar_last, b_last, wlrsz, mb, deg);
  count_deg<<<EB, 256, 0, stream>>>(dst, deg);
  scan_deg<<<1, 1024, 0, stream>>>(deg, off, cursor);
  gemm0_scatter<<<GB + EB, 256, 0, stream>>>(hb, wsz, feat, als, ars, elr, src, dst,
                                             cursor, csr_src);
  fused_small<false><<<FB, 256, 0, stream>>>(off, csr_src, feat, elr, bs, h, hb, nullptr,
                                             nullptr);
  gemm_mfma<DM, false><<<GB, 256, 0, stream>>>(hb, wsz + 16384, nullptr, nullptr, feat,
                                               nullptr, als + 128, ars + 128, elr);
  fused_small<true><<<FB, 256, 0, stream>>>(off, csr_src, feat, elr, bs + 128, h, hb,
                                            wlrsz, elr2);
  fused_last<<<FB, 256, 0, stream>>>(off, csr_src, hb, elr2, g);
  gemm_mfma<NH * DM, true><<<GB, 256, 0, stream>>>(g, wpsz, h, mb, nullptr, out, nullptr,
                                                   nullptr, nullptr);
}

// Round 15
// 184.526 us; speedup vs baseline: 4.4441x; 1.0407x over previous
//
#include <hip/hip_runtime.h>
#include <math.h>

#define N_NODES 20000
#define N_EDGES 200000
#define DM 128
#define NH 8

typedef __attribute__((ext_vector_type(8))) short bf16x8;
typedef __attribute__((ext_vector_type(4))) float f32x4;

__device__ __forceinline__ unsigned short f2b(float f) {
  unsigned int u = __float_as_uint(f);
  unsigned int r = (u + 0x7FFFu + ((u >> 16) & 1u)) >> 16;  // RNE
  return (unsigned short)r;
}
__device__ __forceinline__ float b2f(unsigned short s) {
  return __uint_as_float(((unsigned int)s) << 16);
}

// ---------------- deg zero (must precede prep_all's counting) ----------------
__global__ __launch_bounds__(256) void degzero(int* __restrict__ deg) {
  int i = blockIdx.x * 256 + threadIdx.x;
  if (i < N_NODES) deg[i] = 0;
}

// ---------------- prep: cast + edge count(rank) + all weight prep ----------------
__global__ __launch_bounds__(256) void prep_all(
    const float* __restrict__ x, float* __restrict__ h, unsigned short* __restrict__ hb,
    const int* __restrict__ dstE, int* __restrict__ deg, int* __restrict__ rank,
    const float* __restrict__ Ws, unsigned short* __restrict__ wsz,
    const float* __restrict__ W_last, unsigned short* __restrict__ wpsz,
    const float* __restrict__ al_last, const float* __restrict__ ar_last,
    const float* __restrict__ b_last, unsigned short* __restrict__ wlrsz,
    float* __restrict__ mb) {
  int i = blockIdx.x * 256 + threadIdx.x;
  if (i < (N_NODES * DM) / 4) {  // float4 cast
    float4 v = ((const float4*)x)[i];
    ((float4*)h)[i] = v;
    ((ushort4*)hb)[i] = make_ushort4(f2b(v.x), f2b(v.y), f2b(v.z), f2b(v.w));
  }
  if (i < N_EDGES) rank[i] = atomicAdd(&deg[dstE[i]], 1);
  if (i < 2 * 16384) {  // layers 0/1 B swizzle
    int layer = i >> 14;
    int r = i & 16383;
    int j = r & 7, l = (r >> 3) & 63, f = (r >> 9) & 7, ks = r >> 12;
    int k = ks * 32 + ((l >> 4) << 3) + j;
    int n = f * 16 + (l & 15);
    wsz[i] = f2b(Ws[(size_t)layer * 16384 + k * 128 + n]);
  }
  if (i < 131072) {  // last-layer B swizzle (1/8 mean folded)
    int j = i & 7, l = (i >> 3) & 63, f = (i >> 9) & 7, ks = i >> 12;
    int k = ks * 32 + ((l >> 4) << 3) + j;
    int n = f * 16 + (l & 15);
    int h_ = k >> 7, ko = k & 127;
    wpsz[i] = f2b(W_last[(size_t)ko * 1024 + h_ * 128 + n] * 0.125f);
  }
  if (i < 2048) {  // wlr fragment build
    int j = i & 7, l = (i >> 3) & 63, ks = i >> 9;
    int k = ks * 32 + ((l >> 4) << 3) + j;
    int n = l & 15;
    int hh = n & 7;
    const float* av = (n < 8) ? (al_last + hh * 128) : (ar_last + hh * 128);
    float s = 0.f;
    for (int d = 0; d < 128; ++d) s += W_last[(size_t)k * 1024 + hh * 128 + d] * av[d];
    wlrsz[i] = f2b(s);
  }
  if (i < 128) {
    float s = 0.f;
#pragma unroll
    for (int hh = 0; hh < 8; ++hh) s += b_last[hh * 128 + i];
    mb[i] = s * 0.125f;
  }
}

// ---------------- single-block exclusive scan (off only) ----------------
__global__ void scan_deg(const int* __restrict__ deg, int* __restrict__ off) {
  __shared__ int part[1024];
  const int tid = threadIdx.x;
  const int CHUNK = (N_NODES + 1023) / 1024;  // 20
  int base = tid * CHUNK;
  int s = 0;
  for (int i = 0; i < CHUNK; ++i) {
    int idx = base + i;
    if (idx < N_NODES) s += deg[idx];
  }
  part[tid] = s;
  __syncthreads();
  for (int ofs = 1; ofs < 1024; ofs <<= 1) {
    int v = (tid >= ofs) ? part[tid - ofs] : 0;
    __syncthreads();
    part[tid] += v;
    __syncthreads();
  }
  int run = (tid > 0) ? part[tid - 1] : 0;
  for (int i = 0; i < CHUNK; ++i) {
    int idx = base + i;
    if (idx < N_NODES) {
      off[idx] = run;
      run += deg[idx];
    }
  }
  if (tid == 0) off[N_NODES] = part[1023];
}

// ---------------- MFMA GEMM device body ----------------
template <int K, bool LAST>
__device__ __forceinline__ void dev_gemm(int tile, const unsigned short* __restrict__ A,
                                         const unsigned short* __restrict__ Bsz,
                                         const float* __restrict__ hres,
                                         const float* __restrict__ mbv,
                                         unsigned short* __restrict__ Cb,
                                         float* __restrict__ Cf,
                                         const float* __restrict__ al,
                                         const float* __restrict__ ar,
                                         float* __restrict__ elr, int lane, int wid) {
  const int wrow = wid & 1, wc = wid >> 1;
  const int r0 = tile * 32;
  const int arow = r0 + wrow * 16 + (lane & 15);
  const int kg = lane >> 4;

  f32x4 acc[4];
#pragma unroll
  for (int fi = 0; fi < 4; ++fi) acc[fi] = {0.f, 0.f, 0.f, 0.f};

  const bf16x8* Ap = (const bf16x8*)(A + (size_t)arow * K + kg * 8);
#pragma unroll 4
  for (int ks = 0; ks < K / 32; ++ks) {
    bf16x8 a = Ap[ks * 4];
#pragma unroll
    for (int fi = 0; fi < 4; ++fi) {
      int f = wc * 4 + fi;
      bf16x8 b = *(const bf16x8*)(Bsz + (((size_t)(ks * 8 + f) * 64 + lane) << 3));
      acc[fi] = __builtin_amdgcn_mfma_f32_16x16x32_bf16(a, b, acc[fi], 0, 0, 0);
    }
  }

  const int rbase = r0 + wrow * 16 + (lane >> 4) * 4;
#pragma unroll
  for (int fi = 0; fi < 4; ++fi) {
    int col = wc * 64 + fi * 16 + (lane & 15);
#pragma unroll
    for (int r = 0; r < 4; ++r) {
      int row = rbase + r;
      float v = acc[fi][r];
      if (LAST)
        Cf[(size_t)row * DM + col] = v + hres[(size_t)row * DM + col] + mbv[col];
      else
        Cb[(size_t)row * DM + col] = f2b(v);
    }
  }

  if (!LAST) {
#pragma unroll
    for (int fi = 0; fi < 4; ++fi) {
      int hh = wc * 4 + fi;
      float alv = al[hh * 16 + (lane & 15)];
      float arv = ar[hh * 16 + (lane & 15)];
#pragma unroll
      for (int r = 0; r < 4; ++r) {
        float pl = acc[fi][r] * alv;
        float pr = acc[fi][r] * arv;
#pragma unroll
        for (int msk = 1; msk < 16; msk <<= 1) {
          pl += __shfl_xor(pl, msk, 64);
          pr += __shfl_xor(pr, msk, 64);
        }
        if ((lane & 15) == 0) {
          int row = rbase + r;
          elr[row * 16 + hh] = pl;
          elr[row * 16 + 8 + hh] = pr;
        }
      }
    }
  }
}

// layer0 GEMM || rank-based CSR scatter (non-atomic)
__global__ __launch_bounds__(256) void gemm0_scatter(
    const unsigned short* __restrict__ A, const unsigned short* __restrict__ Bsz,
    unsigned short* __restrict__ Cb, const float* __restrict__ al,
    const float* __restrict__ ar, float* __restrict__ elr, const int* __restrict__ srcE,
    const int* __restrict__ dstE, const int* __restrict__ rank,
    const int* __restrict__ off, int* __restrict__ csr_src) {
  const int bid = blockIdx.x;
  if (bid < N_NODES / 32) {
    dev_gemm<DM, false>(bid, A, Bsz, nullptr, nullptr, Cb, nullptr, al, ar, elr,
                        threadIdx.x & 63, threadIdx.x >> 6);
  } else {
    int e = (bid - N_NODES / 32) * 256 + threadIdx.x;
    if (e < N_EDGES) {
      csr_src[off[dstE[e]] + rank[e]] = srcE[e];
    }
  }
}

template <int K, bool LAST>
__global__ __launch_bounds__(256) void gemm_mfma(
    const unsigned short* __restrict__ A, const unsigned short* __restrict__ Bsz,
    const float* __restrict__ hres, const float* __restrict__ mbv,
    unsigned short* __restrict__ Cb, float* __restrict__ Cf,
    const float* __restrict__ al, const float* __restrict__ ar, float* __restrict__ elr) {
  dev_gemm<K, LAST>(blockIdx.x, A, Bsz, hres, mbv, Cb, Cf, al, ar, elr, threadIdx.x & 63,
                    threadIdx.x >> 6);
}

// ---------------- layers 0/1: fused softmax+agg (+optional elr_last epilogue) ----------------
template <bool ELR>
__global__ __launch_bounds__(256) void fused_small(
    const int* __restrict__ off, const int* __restrict__ csr_src,
    const unsigned short* __restrict__ feat, const float* __restrict__ elr,
    const float* __restrict__ bias, float* __restrict__ h, unsigned short* __restrict__ hb,
    const unsigned short* __restrict__ wlrsz, float* __restrict__ elr_out) {
  __shared__ float a_lds[4][64];
  __shared__ int s_lds[4][8];
  __shared__ float zi_lds[4][8];
  __shared__ __align__(16) unsigned short nh_lds[4][128];
  const int wid = threadIdx.x >> 6;
  const int t = blockIdx.x * 4 + wid;
  const int lane = threadIdx.x & 63;
  const int e_loc = lane >> 3, hh = lane & 7;
  const int hg = lane >> 3;  // head for dims 2*lane, 2*lane+1
  const int beg = off[t], end = off[t + 1];
  const float ert = elr[t * 16 + 8 + hh];

  int e = beg + e_loc;
  bool val = e < end;
  int s = val ? csr_src[e] : 0;
  float xl = val ? elr[s * 16 + hh] : 0.f;

  float z = 0.f, acc0 = 0.f, acc1 = 0.f;
  for (int base = beg; base < end; base += 8) {
    float ex = 0.f;
    if (val) {
      float xv = xl + ert;
      xv = xv > 0.f ? xv : 0.2f * xv;
      ex = __expf(xv);
    }
    a_lds[wid][lane] = ex;
    if (hh == 0) s_lds[wid][e_loc] = s;
    __builtin_amdgcn_wave_barrier();
    asm volatile("s_waitcnt lgkmcnt(0)" ::: "memory");
    z += ex;
    int en = base + 8 + e_loc;
    bool valn = en < end;
    int sn = valn ? csr_src[en] : 0;
    float xln = valn ? elr[sn * 16 + hh] : 0.f;
    int n = min(8, end - base);
    for (int e2 = 0; e2 < n; ++e2) {
      int s2 = s_lds[wid][e2];
      float a = a_lds[wid][e2 * 8 + hg];
      unsigned int hv = *(const unsigned int*)&feat[(size_t)s2 * 128 + 2 * lane];
      acc0 += a * b2f((unsigned short)(hv & 0xffffu));
      acc1 += a * b2f((unsigned short)(hv >> 16));
    }
    __builtin_amdgcn_wave_barrier();
    s = sn;
    xl = xln;
    val = valn;
  }
  z += __shfl_xor(z, 8, 64);
  z += __shfl_xor(z, 16, 64);
  z += __shfl_xor(z, 32, 64);
  if (e_loc == 0) zi_lds[wid][hh] = (z > 0.f) ? 1.f / z : 0.f;
  __builtin_amdgcn_wave_barrier();
  asm volatile("s_waitcnt lgkmcnt(0)" ::: "memory");
  float zi = zi_lds[wid][hg];

  float2 bv = *(const float2*)&bias[2 * lane];
  float v0 = acc0 * zi + bv.x;
  float v1 = acc1 * zi + bv.y;
  v0 = v0 > 0.f ? v0 : expm1f(v0);
  v1 = v1 > 0.f ? v1 : expm1f(v1);
  size_t idx = (size_t)t * 128 + 2 * lane;
  float2 hv = *(const float2*)&h[idx];
  float nh0 = hv.x + v0;
  float nh1 = hv.y + v1;
  *(float2*)&h[idx] = make_float2(nh0, nh1);
  unsigned short b0 = f2b(nh0), b1 = f2b(nh1);
  *(ushort2*)&hb[idx] = make_ushort2(b0, b1);

  if (ELR) {
    // elr_last fused: elr_out[t][0..15] = nh @ [wl|wr] via one MFMA chain
    *(ushort2*)&nh_lds[wid][2 * lane] = make_ushort2(b0, b1);
    __builtin_amdgcn_wave_barrier();
    asm volatile("s_waitcnt lgkmcnt(0)" ::: "memory");
    const int kg = lane >> 4;
    f32x4 acc = {0.f, 0.f, 0.f, 0.f};
#pragma unroll
    for (int ks = 0; ks < 4; ++ks) {
      bf16x8 a = *(const bf16x8*)&nh_lds[wid][ks * 32 + kg * 8];
      bf16x8 b = *(const bf16x8*)(wlrsz + (((size_t)ks * 64 + lane) << 3));
      acc = __builtin_amdgcn_mfma_f32_16x16x32_bf16(a, b, acc, 0, 0, 0);
    }
    if (lane < 16) elr_out[t * 16 + lane] = acc[0];
  }
}

// ---------------- last layer: fused softmax+agg, single pass, pipelined ----------------
__global__ __launch_bounds__(256) void fused_last(
    const int* __restrict__ off, const int* __restrict__ csr_src,
    const unsigned short* __restrict__ hb, const float* __restrict__ elr,
    unsigned short* __restrict__ g) {
  __shared__ float a_lds[4][64];
  __shared__ int s_lds[4][8];
  __shared__ float zi_lds[4][8];
  const int wid = threadIdx.x >> 6;
  const int t = blockIdx.x * 4 + wid;
  const int lane = threadIdx.x & 63;
  const int e_loc = lane >> 3, hh = lane & 7;
  const int beg = off[t], end = off[t + 1];
  const float ert = elr[t * 16 + 8 + hh];

  int e = beg + e_loc;
  bool val = e < end;
  int s = val ? csr_src[e] : 0;
  float xl = val ? elr[s * 16 + hh] : 0.f;

  float z = 0.f;
  float accA[8], accB[8];
#pragma unroll
  for (int k = 0; k < 8; ++k) accA[k] = accB[k] = 0.f;

  for (int base = beg; base < end; base += 8) {
    float ex = 0.f;
    if (val) {
      float xv = xl + ert;
      xv = xv > 0.f ? xv : 0.2f * xv;
      ex = __expf(xv);
    }
    a_lds[wid][lane] = ex;
    if (hh == 0) s_lds[wid][e_loc] = s;
    __builtin_amdgcn_wave_barrier();
    asm volatile("s_waitcnt lgkmcnt(0)" ::: "memory");
    z += ex;
    int en = base + 8 + e_loc;
    bool valn = en < end;
    int sn = valn ? csr_src[en] : 0;
    float xln = valn ? elr[sn * 16 + hh] : 0.f;
    int n = min(8, end - base);
    for (int e2 = 0; e2 < n; ++e2) {
      int s2 = s_lds[wid][e2];
      float4 pa = *(const float4*)&a_lds[wid][e2 * 8];
      float4 pb = *(const float4*)&a_lds[wid][e2 * 8 + 4];
      unsigned int hv = *(const unsigned int*)&hb[(size_t)s2 * 128 + 2 * lane];
      float h0 = b2f((unsigned short)(hv & 0xffffu));
      float h1 = b2f((unsigned short)(hv >> 16));
      accA[0] += pa.x * h0; accB[0] += pa.x * h1;
      accA[1] += pa.y * h0; accB[1] += pa.y * h1;
      accA[2] += pa.z * h0; accB[2] += pa.z * h1;
      accA[3] += pa.w * h0; accB[3] += pa.w * h1;
      accA[4] += pb.x * h0; accB[4] += pb.x * h1;
      accA[5] += pb.y * h0; accB[5] += pb.y * h1;
      accA[6] += pb.z * h0; accB[6] += pb.z * h1;
      accA[7] += pb.w * h0; accB[7] += pb.w * h1;
    }
    __builtin_amdgcn_wave_barrier();
    s = sn;
    xl = xln;
    val = valn;
  }
  z += __shfl_xor(z, 8, 64);
  z += __shfl_xor(z, 16, 64);
  z += __shfl_xor(z, 32, 64);
  if (e_loc == 0) zi_lds[wid][hh] = (z > 0.f) ? 1.f / z : 0.f;
  __builtin_amdgcn_wave_barrier();
  asm volatile("s_waitcnt lgkmcnt(0)" ::: "memory");
  float4 zia = *(const float4*)&zi_lds[wid][0];
  float4 zib = *(const float4*)&zi_lds[wid][4];
  float ziv[8] = {zia.x, zia.y, zia.z, zia.w, zib.x, zib.y, zib.z, zib.w};
#pragma unroll
  for (int h2 = 0; h2 < 8; ++h2) {
    *(ushort2*)&g[(size_t)t * 1024 + h2 * 128 + 2 * lane] =
        make_ushort2(f2b(accA[h2] * ziv[h2]), f2b(accB[h2] * ziv[h2]));
  }
}

extern "C" void kernel_launch(void* const* d_in, const int* in_sizes, int n_in,
                              void* d_out, int out_size, void* d_ws, size_t ws_size,
                              hipStream_t stream) {
  const float* x = (const float*)d_in[0];
  const int* src = (const int*)d_in[1];
  const int* dst = (const int*)d_in[2];
  const float* Ws = (const float*)d_in[3];
  const float* als = (const float*)d_in[4];
  const float* ars = (const float*)d_in[5];
  const float* bs = (const float*)d_in[6];
  const float* W_last = (const float*)d_in[7];
  const float* al_last = (const float*)d_in[8];
  const float* ar_last = (const float*)d_in[9];
  const float* b_last = (const float*)d_in[10];
  float* out = (float*)d_out;

  // ---- workspace layout ----
  float* h = (float*)d_ws;                           // 2,560,000 f
  float* elr = h + 2560000;                          // 320,000 f
  float* elr2 = elr + 320000;                        // 320,000 f (last-layer scores)
  float* mb = elr2 + 320000;                         // 128 f
  unsigned short* hb = (unsigned short*)(mb + 128);  // 2,560,000 us
  unsigned short* feat = hb + 2560000;               // 2,560,000 us
  unsigned short* g = feat + 2560000;                // 20,480,000 us
  unsigned short* wsz = g + 20480000;                // 32,768 us
  unsigned short* wpsz = wsz + 32768;                // 131,072 us
  unsigned short* wlrsz = wpsz + 131072;             // 2,048 us
  int* deg = (int*)(wlrsz + 2048);                   // N
  int* off = deg + N_NODES;                          // N+1
  int* rank = off + N_NODES + 1;                     // E
  int* csr_src = rank + N_EDGES;                     // E

  const int GB = N_NODES / 32;            // 625
  const int FB = N_NODES / 4;             // 5000
  const int EB = (N_EDGES + 255) / 256;   // 782

  degzero<<<(N_NODES + 255) / 256, 256, 0, stream>>>(deg);
  prep_all<<<(N_NODES * DM / 4 + 255) / 256, 256, 0, stream>>>(
      x, h, hb, dst, deg, rank, Ws, wsz, W_last, wpsz, al_last, ar_last, b_last, wlrsz, mb);
  scan_deg<<<1, 1024, 0, stream>>>(deg, off);
  gemm0_scatter<<<GB + EB, 256, 0, stream>>>(hb, wsz, feat, als, ars, elr, src, dst, rank,
                                             off, csr_src);
  fused_small<false><<<FB, 256, 0, stream>>>(off, csr_src, feat, elr, bs, h, hb, nullptr,
                                             nullptr);
  gemm_mfma<DM, false><<<GB, 256, 0, stream>>>(hb, wsz + 16384, nullptr, nullptr, feat,
                                               nullptr, als + 128, ars + 128, elr);
  fused_small<true><<<FB, 256, 0, stream>>>(off, csr_src, feat, elr, bs + 128, h, hb,
                                            wlrsz, elr2);
  fused_last<<<FB, 256, 0, stream>>>(off, csr_src, hb, elr2, g);
  gemm_mfma<NH * DM, true><<<GB, 256, 0, stream>>>(g, wpsz, h, mb, nullptr, out, nullptr,
                                                   nullptr, nullptr);
}

// Round 16
// 176.454 us; speedup vs baseline: 4.6474x; 1.0457x over previous
//
#include <hip/hip_runtime.h>
#include <math.h>

#define N_NODES 20000
#define N_EDGES 200000
#define DM 128
#define NH 8

typedef __attribute__((ext_vector_type(8))) short bf16x8;
typedef __attribute__((ext_vector_type(4))) float f32x4;

__device__ __forceinline__ unsigned short f2b(float f) {
  unsigned int u = __float_as_uint(f);
  unsigned int r = (u + 0x7FFFu + ((u >> 16) & 1u)) >> 16;  // RNE
  return (unsigned short)r;
}
__device__ __forceinline__ float b2f(unsigned short s) {
  return __uint_as_float(((unsigned int)s) << 16);
}

// ---------------- deg zero (must precede prep_all's counting) ----------------
__global__ __launch_bounds__(256) void degzero(int* __restrict__ deg) {
  int i = blockIdx.x * 256 + threadIdx.x;
  if (i < N_NODES) deg[i] = 0;
}

// ---------------- prep: cast + edge count(rank) + all weight prep ----------------
__global__ __launch_bounds__(256) void prep_all(
    const float* __restrict__ x, float* __restrict__ h, unsigned short* __restrict__ hb,
    const int* __restrict__ dstE, int* __restrict__ deg, int* __restrict__ rank,
    const float* __restrict__ Ws, unsigned short* __restrict__ wsz,
    const float* __restrict__ W_last, unsigned short* __restrict__ wpsz,
    const float* __restrict__ al_last, const float* __restrict__ ar_last,
    const float* __restrict__ b_last, unsigned short* __restrict__ wlrsz,
    float* __restrict__ mb) {
  int i = blockIdx.x * 256 + threadIdx.x;
  if (i < (N_NODES * DM) / 4) {  // float4 cast
    float4 v = ((const float4*)x)[i];
    ((float4*)h)[i] = v;
    ((ushort4*)hb)[i] = make_ushort4(f2b(v.x), f2b(v.y), f2b(v.z), f2b(v.w));
  }
  if (i < N_EDGES) rank[i] = atomicAdd(&deg[dstE[i]], 1);
  if (i < 2 * 16384) {  // layers 0/1 B swizzle
    int layer = i >> 14;
    int r = i & 16383;
    int j = r & 7, l = (r >> 3) & 63, f = (r >> 9) & 7, ks = r >> 12;
    int k = ks * 32 + ((l >> 4) << 3) + j;
    int n = f * 16 + (l & 15);
    wsz[i] = f2b(Ws[(size_t)layer * 16384 + k * 128 + n]);
  }
  if (i < 131072) {  // last-layer B swizzle (1/8 mean folded)
    int j = i & 7, l = (i >> 3) & 63, f = (i >> 9) & 7, ks = i >> 12;
    int k = ks * 32 + ((l >> 4) << 3) + j;
    int n = f * 16 + (l & 15);
    int h_ = k >> 7, ko = k & 127;
    wpsz[i] = f2b(W_last[(size_t)ko * 1024 + h_ * 128 + n] * 0.125f);
  }
  if (i < 2048) {  // wlr fragment build
    int j = i & 7, l = (i >> 3) & 63, ks = i >> 9;
    int k = ks * 32 + ((l >> 4) << 3) + j;
    int n = l & 15;
    int hh = n & 7;
    const float* av = (n < 8) ? (al_last + hh * 128) : (ar_last + hh * 128);
    float s = 0.f;
    for (int d = 0; d < 128; ++d) s += W_last[(size_t)k * 1024 + hh * 128 + d] * av[d];
    wlrsz[i] = f2b(s);
  }
  if (i < 128) {
    float s = 0.f;
#pragma unroll
    for (int hh = 0; hh < 8; ++hh) s += b_last[hh * 128 + i];
    mb[i] = s * 0.125f;
  }
}

// ---------------- single-block exclusive scan (off only) ----------------
__global__ void scan_deg(const int* __restrict__ deg, int* __restrict__ off) {
  __shared__ int part[1024];
  const int tid = threadIdx.x;
  const int CHUNK = (N_NODES + 1023) / 1024;  // 20
  int base = tid * CHUNK;
  int s = 0;
  for (int i = 0; i < CHUNK; ++i) {
    int idx = base + i;
    if (idx < N_NODES) s += deg[idx];
  }
  part[tid] = s;
  __syncthreads();
  for (int ofs = 1; ofs < 1024; ofs <<= 1) {
    int v = (tid >= ofs) ? part[tid - ofs] : 0;
    __syncthreads();
    part[tid] += v;
    __syncthreads();
  }
  int run = (tid > 0) ? part[tid - 1] : 0;
  for (int i = 0; i < CHUNK; ++i) {
    int idx = base + i;
    if (idx < N_NODES) {
      off[idx] = run;
      run += deg[idx];
    }
  }
  if (tid == 0) off[N_NODES] = part[1023];
}

// ---------------- MFMA GEMM device body (layers 0/1) ----------------
template <int K>
__device__ __forceinline__ void dev_gemm(int tile, const unsigned short* __restrict__ A,
                                         const unsigned short* __restrict__ Bsz,
                                         unsigned short* __restrict__ Cb,
                                         const float* __restrict__ al,
                                         const float* __restrict__ ar,
                                         float* __restrict__ elr, int lane, int wid) {
  const int wrow = wid & 1, wc = wid >> 1;
  const int r0 = tile * 32;
  const int arow = r0 + wrow * 16 + (lane & 15);
  const int kg = lane >> 4;

  f32x4 acc[4];
#pragma unroll
  for (int fi = 0; fi < 4; ++fi) acc[fi] = {0.f, 0.f, 0.f, 0.f};

  const bf16x8* Ap = (const bf16x8*)(A + (size_t)arow * K + kg * 8);
#pragma unroll 4
  for (int ks = 0; ks < K / 32; ++ks) {
    bf16x8 a = Ap[ks * 4];
#pragma unroll
    for (int fi = 0; fi < 4; ++fi) {
      int f = wc * 4 + fi;
      bf16x8 b = *(const bf16x8*)(Bsz + (((size_t)(ks * 8 + f) * 64 + lane) << 3));
      acc[fi] = __builtin_amdgcn_mfma_f32_16x16x32_bf16(a, b, acc[fi], 0, 0, 0);
    }
  }

  const int rbase = r0 + wrow * 16 + (lane >> 4) * 4;
#pragma unroll
  for (int fi = 0; fi < 4; ++fi) {
    int col = wc * 64 + fi * 16 + (lane & 15);
#pragma unroll
    for (int r = 0; r < 4; ++r) {
      Cb[(size_t)(rbase + r) * DM + col] = f2b(acc[fi][r]);
    }
  }

  // fused attn scores: head hh = wc*4+fi owns cols hh*16+(lane&15)
#pragma unroll
  for (int fi = 0; fi < 4; ++fi) {
    int hh = wc * 4 + fi;
    float alv = al[hh * 16 + (lane & 15)];
    float arv = ar[hh * 16 + (lane & 15)];
#pragma unroll
    for (int r = 0; r < 4; ++r) {
      float pl = acc[fi][r] * alv;
      float pr = acc[fi][r] * arv;
#pragma unroll
      for (int msk = 1; msk < 16; msk <<= 1) {
        pl += __shfl_xor(pl, msk, 64);
        pr += __shfl_xor(pr, msk, 64);
      }
      if ((lane & 15) == 0) {
        int row = rbase + r;
        elr[row * 16 + hh] = pl;
        elr[row * 16 + 8 + hh] = pr;
      }
    }
  }
}

// layer0 GEMM || rank-based CSR scatter (non-atomic)
__global__ __launch_bounds__(256) void gemm0_scatter(
    const unsigned short* __restrict__ A, const unsigned short* __restrict__ Bsz,
    unsigned short* __restrict__ Cb, const float* __restrict__ al,
    const float* __restrict__ ar, float* __restrict__ elr, const int* __restrict__ srcE,
    const int* __restrict__ dstE, const int* __restrict__ rank,
    const int* __restrict__ off, int* __restrict__ csr_src) {
  const int bid = blockIdx.x;
  if (bid < N_NODES / 32) {
    dev_gemm<DM>(bid, A, Bsz, Cb, al, ar, elr, threadIdx.x & 63, threadIdx.x >> 6);
  } else {
    int e = (bid - N_NODES / 32) * 256 + threadIdx.x;
    if (e < N_EDGES) {
      csr_src[off[dstE[e]] + rank[e]] = srcE[e];
    }
  }
}

__global__ __launch_bounds__(256) void gemm_mfma(
    const unsigned short* __restrict__ A, const unsigned short* __restrict__ Bsz,
    unsigned short* __restrict__ Cb, const float* __restrict__ al,
    const float* __restrict__ ar, float* __restrict__ elr) {
  dev_gemm<DM>(blockIdx.x, A, Bsz, Cb, al, ar, elr, threadIdx.x & 63, threadIdx.x >> 6);
}

// ---------------- layers 0/1: fused softmax+agg (+optional elr_last epilogue) ----------------
template <bool ELR>
__global__ __launch_bounds__(256) void fused_small(
    const int* __restrict__ off, const int* __restrict__ csr_src,
    const unsigned short* __restrict__ feat, const float* __restrict__ elr,
    const float* __restrict__ bias, float* __restrict__ h, unsigned short* __restrict__ hb,
    const unsigned short* __restrict__ wlrsz, float* __restrict__ elr_out) {
  __shared__ float a_lds[4][64];
  __shared__ int s_lds[4][8];
  __shared__ float zi_lds[4][8];
  __shared__ __align__(16) unsigned short nh_lds[4][128];
  const int wid = threadIdx.x >> 6;
  const int t = blockIdx.x * 4 + wid;
  const int lane = threadIdx.x & 63;
  const int e_loc = lane >> 3, hh = lane & 7;
  const int hg = lane >> 3;  // head for dims 2*lane, 2*lane+1
  const int beg = off[t], end = off[t + 1];
  const float ert = elr[t * 16 + 8 + hh];

  int e = beg + e_loc;
  bool val = e < end;
  int s = val ? csr_src[e] : 0;
  float xl = val ? elr[s * 16 + hh] : 0.f;

  float z = 0.f, acc0 = 0.f, acc1 = 0.f;
  for (int base = beg; base < end; base += 8) {
    float ex = 0.f;
    if (val) {
      float xv = xl + ert;
      xv = xv > 0.f ? xv : 0.2f * xv;
      ex = __expf(xv);
    }
    a_lds[wid][lane] = ex;
    if (hh == 0) s_lds[wid][e_loc] = s;
    __builtin_amdgcn_wave_barrier();
    asm volatile("s_waitcnt lgkmcnt(0)" ::: "memory");
    z += ex;
    int en = base + 8 + e_loc;
    bool valn = en < end;
    int sn = valn ? csr_src[en] : 0;
    float xln = valn ? elr[sn * 16 + hh] : 0.f;
    int n = min(8, end - base);
    for (int e2 = 0; e2 < n; ++e2) {
      int s2 = s_lds[wid][e2];
      float a = a_lds[wid][e2 * 8 + hg];
      unsigned int hv = *(const unsigned int*)&feat[(size_t)s2 * 128 + 2 * lane];
      acc0 += a * b2f((unsigned short)(hv & 0xffffu));
      acc1 += a * b2f((unsigned short)(hv >> 16));
    }
    __builtin_amdgcn_wave_barrier();
    s = sn;
    xl = xln;
    val = valn;
  }
  z += __shfl_xor(z, 8, 64);
  z += __shfl_xor(z, 16, 64);
  z += __shfl_xor(z, 32, 64);
  if (e_loc == 0) zi_lds[wid][hh] = (z > 0.f) ? 1.f / z : 0.f;
  __builtin_amdgcn_wave_barrier();
  asm volatile("s_waitcnt lgkmcnt(0)" ::: "memory");
  float zi = zi_lds[wid][hg];

  float2 bv = *(const float2*)&bias[2 * lane];
  float v0 = acc0 * zi + bv.x;
  float v1 = acc1 * zi + bv.y;
  v0 = v0 > 0.f ? v0 : expm1f(v0);
  v1 = v1 > 0.f ? v1 : expm1f(v1);
  size_t idx = (size_t)t * 128 + 2 * lane;
  float2 hv = *(const float2*)&h[idx];
  float nh0 = hv.x + v0;
  float nh1 = hv.y + v1;
  *(float2*)&h[idx] = make_float2(nh0, nh1);
  unsigned short b0 = f2b(nh0), b1 = f2b(nh1);
  *(ushort2*)&hb[idx] = make_ushort2(b0, b1);

  if (ELR) {
    // elr_last fused: elr_out[t][0..15] = nh @ [wl|wr] via one MFMA chain
    *(ushort2*)&nh_lds[wid][2 * lane] = make_ushort2(b0, b1);
    __builtin_amdgcn_wave_barrier();
    asm volatile("s_waitcnt lgkmcnt(0)" ::: "memory");
    const int kg = lane >> 4;
    f32x4 acc = {0.f, 0.f, 0.f, 0.f};
#pragma unroll
    for (int ks = 0; ks < 4; ++ks) {
      bf16x8 a = *(const bf16x8*)&nh_lds[wid][ks * 32 + kg * 8];
      bf16x8 b = *(const bf16x8*)(wlrsz + (((size_t)ks * 64 + lane) << 3));
      acc = __builtin_amdgcn_mfma_f32_16x16x32_bf16(a, b, acc, 0, 0, 0);
    }
    if (lane < 16) elr_out[t * 16 + lane] = acc[0];
  }
}

// ---------------- last layer: fused agg (1 node/wave, 16 waves) + in-block GEMM ----------------
// Block = 1024 thr = 16 waves. Phase 1: wave wid aggregates node t0+wid into LDS gt (bf16).
// Phase 2: out[16,128] = gt @ wpsz + h + mb. 16 waves = 8 frag-cols x 2 K-halves.
#define GT_STRIDE 1032
__global__ __launch_bounds__(1024) void agg_gemm16(
    const int* __restrict__ off, const int* __restrict__ csr_src,
    const unsigned short* __restrict__ hb, const float* __restrict__ elr,
    const unsigned short* __restrict__ wpsz, const float* __restrict__ hres,
    const float* __restrict__ mb, float* __restrict__ out) {
  __shared__ __align__(16) unsigned short gt[16][GT_STRIDE];
  __shared__ float red[8][64][4];
  __shared__ float a_lds[16][64];
  __shared__ int s_lds[16][8];
  __shared__ float zi_lds[16][8];
  const int wid = threadIdx.x >> 6;
  const int lane = threadIdx.x & 63;
  const int t0 = blockIdx.x * 16;
  const int t = t0 + wid;
  const int e_loc = lane >> 3, hh = lane & 7;

  // ---- phase 1: aggregate node t (identical body to fused_last, 1 node/wave) ----
  {
    const int beg = off[t], end = off[t + 1];
    const float ert = elr[t * 16 + 8 + hh];
    int e = beg + e_loc;
    bool val = e < end;
    int s = val ? csr_src[e] : 0;
    float xl = val ? elr[s * 16 + hh] : 0.f;

    float z = 0.f;
    float accA[8], accB[8];
#pragma unroll
    for (int k = 0; k < 8; ++k) accA[k] = accB[k] = 0.f;

    for (int base = beg; base < end; base += 8) {
      float ex = 0.f;
      if (val) {
        float xv = xl + ert;
        xv = xv > 0.f ? xv : 0.2f * xv;
        ex = __expf(xv);
      }
      a_lds[wid][lane] = ex;
      if (hh == 0) s_lds[wid][e_loc] = s;
      __builtin_amdgcn_wave_barrier();
      asm volatile("s_waitcnt lgkmcnt(0)" ::: "memory");
      z += ex;
      int en = base + 8 + e_loc;
      bool valn = en < end;
      int sn = valn ? csr_src[en] : 0;
      float xln = valn ? elr[sn * 16 + hh] : 0.f;
      int n = min(8, end - base);
      for (int e2 = 0; e2 < n; ++e2) {
        int s2 = s_lds[wid][e2];
        float4 pa = *(const float4*)&a_lds[wid][e2 * 8];
        float4 pb = *(const float4*)&a_lds[wid][e2 * 8 + 4];
        unsigned int hv = *(const unsigned int*)&hb[(size_t)s2 * 128 + 2 * lane];
        float h0 = b2f((unsigned short)(hv & 0xffffu));
        float h1 = b2f((unsigned short)(hv >> 16));
        accA[0] += pa.x * h0; accB[0] += pa.x * h1;
        accA[1] += pa.y * h0; accB[1] += pa.y * h1;
        accA[2] += pa.z * h0; accB[2] += pa.z * h1;
        accA[3] += pa.w * h0; accB[3] += pa.w * h1;
        accA[4] += pb.x * h0; accB[4] += pb.x * h1;
        accA[5] += pb.y * h0; accB[5] += pb.y * h1;
        accA[6] += pb.z * h0; accB[6] += pb.z * h1;
        accA[7] += pb.w * h0; accB[7] += pb.w * h1;
      }
      __builtin_amdgcn_wave_barrier();
      s = sn;
      xl = xln;
      val = valn;
    }
    z += __shfl_xor(z, 8, 64);
    z += __shfl_xor(z, 16, 64);
    z += __shfl_xor(z, 32, 64);
    if (e_loc == 0) zi_lds[wid][hh] = (z > 0.f) ? 1.f / z : 0.f;
    __builtin_amdgcn_wave_barrier();
    asm volatile("s_waitcnt lgkmcnt(0)" ::: "memory");
    float4 zia = *(const float4*)&zi_lds[wid][0];
    float4 zib = *(const float4*)&zi_lds[wid][4];
    float ziv[8] = {zia.x, zia.y, zia.z, zia.w, zib.x, zib.y, zib.z, zib.w};
#pragma unroll
    for (int h2 = 0; h2 < 8; ++h2) {
      *(ushort2*)&gt[wid][h2 * 128 + 2 * lane] =
          make_ushort2(f2b(accA[h2] * ziv[h2]), f2b(accB[h2] * ziv[h2]));
    }
  }
  __syncthreads();

  // ---- phase 2: out[16,128] = gt @ wpsz + hres + mb ----
  const int f = wid & 7;    // fragment col block (16 cols)
  const int kh = wid >> 3;  // K half
  const int ar16 = lane & 15;
  const int kg = lane >> 4;
  f32x4 acc = {0.f, 0.f, 0.f, 0.f};
#pragma unroll 4
  for (int ksl = 0; ksl < 16; ++ksl) {
    int ks = kh * 16 + ksl;
    bf16x8 a = *(const bf16x8*)&gt[ar16][ks * 32 + kg * 8];
    bf16x8 b = *(const bf16x8*)(wpsz + (((size_t)(ks * 8 + f) * 64 + lane) << 3));
    acc = __builtin_amdgcn_mfma_f32_16x16x32_bf16(a, b, acc, 0, 0, 0);
  }
  if (kh == 1) {
    *(float4*)&red[f][lane][0] = make_float4(acc[0], acc[1], acc[2], acc[3]);
  }
  __syncthreads();
  if (kh == 0) {
    float4 p = *(const float4*)&red[f][lane][0];
    const int col = f * 16 + (lane & 15);
    const int rb = (lane >> 4) * 4;
    float r4[4] = {p.x, p.y, p.z, p.w};
#pragma unroll
    for (int r = 0; r < 4; ++r) {
      int row = t0 + rb + r;
      out[(size_t)row * 128 + col] =
          acc[r] + r4[r] + hres[(size_t)row * 128 + col] + mb[col];
    }
  }
}

extern "C" void kernel_launch(void* const* d_in, const int* in_sizes, int n_in,
                              void* d_out, int out_size, void* d_ws, size_t ws_size,
                              hipStream_t stream) {
  const float* x = (const float*)d_in[0];
  const int* src = (const int*)d_in[1];
  const int* dst = (const int*)d_in[2];
  const float* Ws = (const float*)d_in[3];
  const float* als = (const float*)d_in[4];
  const float* ars = (const float*)d_in[5];
  const float* bs = (const float*)d_in[6];
  const float* W_last = (const float*)d_in[7];
  const float* al_last = (const float*)d_in[8];
  const float* ar_last = (const float*)d_in[9];
  const float* b_last = (const float*)d_in[10];
  float* out = (float*)d_out;

  // ---- workspace layout ----
  float* h = (float*)d_ws;                           // 2,560,000 f
  float* elr = h + 2560000;                          // 320,000 f
  float* elr2 = elr + 320000;                        // 320,000 f (last-layer scores)
  float* mb = elr2 + 320000;                         // 128 f
  unsigned short* hb = (unsigned short*)(mb + 128);  // 2,560,000 us
  unsigned short* feat = hb + 2560000;               // 2,560,000 us
  unsigned short* wsz = feat + 2560000;              // 32,768 us
  unsigned short* wpsz = wsz + 32768;                // 131,072 us
  unsigned short* wlrsz = wpsz + 131072;             // 2,048 us
  int* deg = (int*)(wlrsz + 2048);                   // N
  int* off = deg + N_NODES;                          // N+1
  int* rank = off + N_NODES + 1;                     // E
  int* csr_src = rank + N_EDGES;                     // E

  const int GB = N_NODES / 32;            // 625
  const int FB = N_NODES / 4;             // 5000
  const int EB = (N_EDGES + 255) / 256;   // 782

  degzero<<<(N_NODES + 255) / 256, 256, 0, stream>>>(deg);
  prep_all<<<(N_NODES * DM / 4 + 255) / 256, 256, 0, stream>>>(
      x, h, hb, dst, deg, rank, Ws, wsz, W_last, wpsz, al_last, ar_last, b_last, wlrsz, mb);
  scan_deg<<<1, 1024, 0, stream>>>(deg, off);
  gemm0_scatter<<<GB + EB, 256, 0, stream>>>(hb, wsz, feat, als, ars, elr, src, dst, rank,
                                             off, csr_src);
  fused_small<false><<<FB, 256, 0, stream>>>(off, csr_src, feat, elr, bs, h, hb, nullptr,
                                             nullptr);
  gemm_mfma<<<GB, 256, 0, stream>>>(hb, wsz + 16384, feat, als + 128, ars + 128, elr);
  fused_small<true><<<FB, 256, 0, stream>>>(off, csr_src, feat, elr, bs + 128, h, hb,
                                            wlrsz, elr2);
  agg_gemm16<<<N_NODES / 16, 1024, 0, stream>>>(off, csr_src, hb, elr2, wpsz, h, mb, out);
}

// Round 17
// 167.615 us; speedup vs baseline: 4.8925x; 1.0527x over previous
//
#include <hip/hip_runtime.h>
#include <math.h>

#define N_NODES 20000
#define N_EDGES 200000
#define DM 128
#define NH 8

typedef __attribute__((ext_vector_type(8))) short bf16x8;
typedef __attribute__((ext_vector_type(4))) float f32x4;

__device__ __forceinline__ unsigned short f2b(float f) {
  unsigned int u = __float_as_uint(f);
  unsigned int r = (u + 0x7FFFu + ((u >> 16) & 1u)) >> 16;  // RNE
  return (unsigned short)r;
}
__device__ __forceinline__ float b2f(unsigned short s) {
  return __uint_as_float(((unsigned int)s) << 16);
}

// ---------------- deg zero (must precede prep_all's counting) ----------------
__global__ __launch_bounds__(256) void degzero(int* __restrict__ deg) {
  int i = blockIdx.x * 256 + threadIdx.x;
  if (i < N_NODES) deg[i] = 0;
}

// ---------------- prep: cast + edge count(rank) + all weight prep ----------------
__global__ __launch_bounds__(256) void prep_all(
    const float* __restrict__ x, float* __restrict__ h, unsigned short* __restrict__ hb,
    const int* __restrict__ dstE, int* __restrict__ deg, int* __restrict__ rank,
    const float* __restrict__ Ws, unsigned short* __restrict__ wsz,
    const float* __restrict__ W_last, unsigned short* __restrict__ wpsz,
    const float* __restrict__ al_last, const float* __restrict__ ar_last,
    const float* __restrict__ b_last, unsigned short* __restrict__ wlrsz,
    float* __restrict__ mb) {
  int i = blockIdx.x * 256 + threadIdx.x;
  if (i < (N_NODES * DM) / 4) {  // float4 cast
    float4 v = ((const float4*)x)[i];
    ((float4*)h)[i] = v;
    ((ushort4*)hb)[i] = make_ushort4(f2b(v.x), f2b(v.y), f2b(v.z), f2b(v.w));
  }
  if (i < N_EDGES) rank[i] = atomicAdd(&deg[dstE[i]], 1);
  if (i < 2 * 16384) {  // layers 0/1 B swizzle
    int layer = i >> 14;
    int r = i & 16383;
    int j = r & 7, l = (r >> 3) & 63, f = (r >> 9) & 7, ks = r >> 12;
    int k = ks * 32 + ((l >> 4) << 3) + j;
    int n = f * 16 + (l & 15);
    wsz[i] = f2b(Ws[(size_t)layer * 16384 + k * 128 + n]);
  }
  if (i < 131072) {  // last-layer B swizzle (1/8 mean folded)
    int j = i & 7, l = (i >> 3) & 63, f = (i >> 9) & 7, ks = i >> 12;
    int k = ks * 32 + ((l >> 4) << 3) + j;
    int n = f * 16 + (l & 15);
    int h_ = k >> 7, ko = k & 127;
    wpsz[i] = f2b(W_last[(size_t)ko * 1024 + h_ * 128 + n] * 0.125f);
  }
  if (i < 2048) {  // wlr fragment build
    int j = i & 7, l = (i >> 3) & 63, ks = i >> 9;
    int k = ks * 32 + ((l >> 4) << 3) + j;
    int n = l & 15;
    int hh = n & 7;
    const float* av = (n < 8) ? (al_last + hh * 128) : (ar_last + hh * 128);
    float s = 0.f;
    for (int d = 0; d < 128; ++d) s += W_last[(size_t)k * 1024 + hh * 128 + d] * av[d];
    wlrsz[i] = f2b(s);
  }
  if (i < 128) {
    float s = 0.f;
#pragma unroll
    for (int hh = 0; hh < 8; ++hh) s += b_last[hh * 128 + i];
    mb[i] = s * 0.125f;
  }
}

// ---------------- single-block exclusive scan (off only) ----------------
__global__ void scan_deg(const int* __restrict__ deg, int* __restrict__ off) {
  __shared__ int part[1024];
  const int tid = threadIdx.x;
  const int CHUNK = (N_NODES + 1023) / 1024;  // 20
  int base = tid * CHUNK;
  int s = 0;
  for (int i = 0; i < CHUNK; ++i) {
    int idx = base + i;
    if (idx < N_NODES) s += deg[idx];
  }
  part[tid] = s;
  __syncthreads();
  for (int ofs = 1; ofs < 1024; ofs <<= 1) {
    int v = (tid >= ofs) ? part[tid - ofs] : 0;
    __syncthreads();
    part[tid] += v;
    __syncthreads();
  }
  int run = (tid > 0) ? part[tid - 1] : 0;
  for (int i = 0; i < CHUNK; ++i) {
    int idx = base + i;
    if (idx < N_NODES) {
      off[idx] = run;
      run += deg[idx];
    }
  }
  if (tid == 0) off[N_NODES] = part[1023];
}

// ---------------- MFMA GEMM device body (layer 0) ----------------
template <int K>
__device__ __forceinline__ void dev_gemm(int tile, const unsigned short* __restrict__ A,
                                         const unsigned short* __restrict__ Bsz,
                                         unsigned short* __restrict__ Cb,
                                         const float* __restrict__ al,
                                         const float* __restrict__ ar,
                                         float* __restrict__ elr, int lane, int wid) {
  const int wrow = wid & 1, wc = wid >> 1;
  const int r0 = tile * 32;
  const int arow = r0 + wrow * 16 + (lane & 15);
  const int kg = lane >> 4;

  f32x4 acc[4];
#pragma unroll
  for (int fi = 0; fi < 4; ++fi) acc[fi] = {0.f, 0.f, 0.f, 0.f};

  const bf16x8* Ap = (const bf16x8*)(A + (size_t)arow * K + kg * 8);
#pragma unroll 4
  for (int ks = 0; ks < K / 32; ++ks) {
    bf16x8 a = Ap[ks * 4];
#pragma unroll
    for (int fi = 0; fi < 4; ++fi) {
      int f = wc * 4 + fi;
      bf16x8 b = *(const bf16x8*)(Bsz + (((size_t)(ks * 8 + f) * 64 + lane) << 3));
      acc[fi] = __builtin_amdgcn_mfma_f32_16x16x32_bf16(a, b, acc[fi], 0, 0, 0);
    }
  }

  const int rbase = r0 + wrow * 16 + (lane >> 4) * 4;
#pragma unroll
  for (int fi = 0; fi < 4; ++fi) {
    int col = wc * 64 + fi * 16 + (lane & 15);
#pragma unroll
    for (int r = 0; r < 4; ++r) {
      Cb[(size_t)(rbase + r) * DM + col] = f2b(acc[fi][r]);
    }
  }

  // fused attn scores: head hh = wc*4+fi owns cols hh*16+(lane&15)
#pragma unroll
  for (int fi = 0; fi < 4; ++fi) {
    int hh = wc * 4 + fi;
    float alv = al[hh * 16 + (lane & 15)];
    float arv = ar[hh * 16 + (lane & 15)];
#pragma unroll
    for (int r = 0; r < 4; ++r) {
      float pl = acc[fi][r] * alv;
      float pr = acc[fi][r] * arv;
#pragma unroll
      for (int msk = 1; msk < 16; msk <<= 1) {
        pl += __shfl_xor(pl, msk, 64);
        pr += __shfl_xor(pr, msk, 64);
      }
      if ((lane & 15) == 0) {
        int row = rbase + r;
        elr[row * 16 + hh] = pl;
        elr[row * 16 + 8 + hh] = pr;
      }
    }
  }
}

// layer0 GEMM || rank-based CSR scatter (non-atomic)
__global__ __launch_bounds__(256) void gemm0_scatter(
    const unsigned short* __restrict__ A, const unsigned short* __restrict__ Bsz,
    unsigned short* __restrict__ Cb, const float* __restrict__ al,
    const float* __restrict__ ar, float* __restrict__ elr, const int* __restrict__ srcE,
    const int* __restrict__ dstE, const int* __restrict__ rank,
    const int* __restrict__ off, int* __restrict__ csr_src) {
  const int bid = blockIdx.x;
  if (bid < N_NODES / 32) {
    dev_gemm<DM>(bid, A, Bsz, Cb, al, ar, elr, threadIdx.x & 63, threadIdx.x >> 6);
  } else {
    int e = (bid - N_NODES / 32) * 256 + threadIdx.x;
    if (e < N_EDGES) {
      csr_src[off[dstE[e]] + rank[e]] = srcE[e];
    }
  }
}

// ---------------- layers 0/1: fused softmax+agg ----------------
// MODE 0 (layer 0): epilogue computes feat1 = nh @ W1 + layer-1 scores (separate out bufs).
// MODE 1 (layer 1): epilogue computes elr2 = nh @ [wl|wr] (elr_last).
template <int MODE>
__global__ __launch_bounds__(256) void fused_small(
    const int* __restrict__ off, const int* __restrict__ csr_src,
    const unsigned short* __restrict__ feat, const float* __restrict__ elr,
    const float* __restrict__ bias, float* __restrict__ h, unsigned short* __restrict__ hb,
    const unsigned short* __restrict__ wsz1, const float* __restrict__ al1,
    const float* __restrict__ ar1, unsigned short* __restrict__ feat_out,
    float* __restrict__ elr_out, const unsigned short* __restrict__ wlrsz,
    float* __restrict__ elr2_out) {
  __shared__ float a_lds[4][64];
  __shared__ int s_lds[4][8];
  __shared__ float zi_lds[4][8];
  __shared__ __align__(16) unsigned short nh_lds[4][128];
  const int wid = threadIdx.x >> 6;
  const int t = blockIdx.x * 4 + wid;
  const int lane = threadIdx.x & 63;
  const int e_loc = lane >> 3, hh = lane & 7;
  const int hg = lane >> 3;  // head for dims 2*lane, 2*lane+1
  const int beg = off[t], end = off[t + 1];
  const float ert = elr[t * 16 + 8 + hh];

  int e = beg + e_loc;
  bool val = e < end;
  int s = val ? csr_src[e] : 0;
  float xl = val ? elr[s * 16 + hh] : 0.f;

  float z = 0.f, acc0 = 0.f, acc1 = 0.f;
  for (int base = beg; base < end; base += 8) {
    float ex = 0.f;
    if (val) {
      float xv = xl + ert;
      xv = xv > 0.f ? xv : 0.2f * xv;
      ex = __expf(xv);
    }
    a_lds[wid][lane] = ex;
    if (hh == 0) s_lds[wid][e_loc] = s;
    __builtin_amdgcn_wave_barrier();
    asm volatile("s_waitcnt lgkmcnt(0)" ::: "memory");
    z += ex;
    int en = base + 8 + e_loc;
    bool valn = en < end;
    int sn = valn ? csr_src[en] : 0;
    float xln = valn ? elr[sn * 16 + hh] : 0.f;
    int n = min(8, end - base);
    if (n == 8) {
#pragma unroll
      for (int e2 = 0; e2 < 8; ++e2) {
        int s2 = s_lds[wid][e2];
        float a = a_lds[wid][e2 * 8 + hg];
        unsigned int hv = *(const unsigned int*)&feat[(size_t)s2 * 128 + 2 * lane];
        acc0 += a * b2f((unsigned short)(hv & 0xffffu));
        acc1 += a * b2f((unsigned short)(hv >> 16));
      }
    } else {
      for (int e2 = 0; e2 < n; ++e2) {
        int s2 = s_lds[wid][e2];
        float a = a_lds[wid][e2 * 8 + hg];
        unsigned int hv = *(const unsigned int*)&feat[(size_t)s2 * 128 + 2 * lane];
        acc0 += a * b2f((unsigned short)(hv & 0xffffu));
        acc1 += a * b2f((unsigned short)(hv >> 16));
      }
    }
    __builtin_amdgcn_wave_barrier();
    s = sn;
    xl = xln;
    val = valn;
  }
  z += __shfl_xor(z, 8, 64);
  z += __shfl_xor(z, 16, 64);
  z += __shfl_xor(z, 32, 64);
  if (e_loc == 0) zi_lds[wid][hh] = (z > 0.f) ? 1.f / z : 0.f;
  __builtin_amdgcn_wave_barrier();
  asm volatile("s_waitcnt lgkmcnt(0)" ::: "memory");
  float zi = zi_lds[wid][hg];

  float2 bv = *(const float2*)&bias[2 * lane];
  float v0 = acc0 * zi + bv.x;
  float v1 = acc1 * zi + bv.y;
  v0 = v0 > 0.f ? v0 : expm1f(v0);
  v1 = v1 > 0.f ? v1 : expm1f(v1);
  size_t idx = (size_t)t * 128 + 2 * lane;
  float2 hv = *(const float2*)&h[idx];
  float nh0 = hv.x + v0;
  float nh1 = hv.y + v1;
  *(float2*)&h[idx] = make_float2(nh0, nh1);
  unsigned short b0 = f2b(nh0), b1 = f2b(nh1);
  *(ushort2*)&hb[idx] = make_ushort2(b0, b1);
  *(ushort2*)&nh_lds[wid][2 * lane] = make_ushort2(b0, b1);

  if (MODE == 1) {
    // elr_last fused: elr2_out[t][0..15] = nh @ [wl|wr] via one MFMA chain
    __builtin_amdgcn_wave_barrier();
    asm volatile("s_waitcnt lgkmcnt(0)" ::: "memory");
    const int kg = lane >> 4;
    f32x4 acc = {0.f, 0.f, 0.f, 0.f};
#pragma unroll
    for (int ks = 0; ks < 4; ++ks) {
      bf16x8 a = *(const bf16x8*)&nh_lds[wid][ks * 32 + kg * 8];
      bf16x8 b = *(const bf16x8*)(wlrsz + (((size_t)ks * 64 + lane) << 3));
      acc = __builtin_amdgcn_mfma_f32_16x16x32_bf16(a, b, acc, 0, 0, 0);
    }
    if (lane < 16) elr2_out[t * 16 + lane] = acc[0];
  }

  if (MODE == 0) {
    // fused layer-1 GEMM: feat_out[4 rows] = nh @ W1, + layer-1 el/er scores.
    // A rows 0-3 = block's 4 nodes (from nh_lds), rows 4-15 zero.
    __syncthreads();
    const int t0b = blockIdx.x * 4;
    const int r16 = lane & 15;
    const int kg = lane >> 4;
    f32x4 acc2[2];
    acc2[0] = {0.f, 0.f, 0.f, 0.f};
    acc2[1] = {0.f, 0.f, 0.f, 0.f};
#pragma unroll
    for (int ks = 0; ks < 4; ++ks) {
      bf16x8 a = {0, 0, 0, 0, 0, 0, 0, 0};
      if (r16 < 4) a = *(const bf16x8*)&nh_lds[r16][ks * 32 + kg * 8];
#pragma unroll
      for (int fi = 0; fi < 2; ++fi) {
        int f = wid * 2 + fi;
        bf16x8 b = *(const bf16x8*)(wsz1 + (((size_t)(ks * 8 + f) * 64 + lane) << 3));
        acc2[fi] = __builtin_amdgcn_mfma_f32_16x16x32_bf16(a, b, acc2[fi], 0, 0, 0);
      }
    }
    const int rowl = (lane >> 4) * 4;  // row group base: rows rowl..rowl+3 (valid only 0-3)
#pragma unroll
    for (int fi = 0; fi < 2; ++fi) {
      int f = wid * 2 + fi;  // fragment = head (hd=16)
      int col = f * 16 + r16;
      float alv = al1[col];
      float arv = ar1[col];
#pragma unroll
      for (int r = 0; r < 4; ++r) {
        float v = acc2[fi][r];
        if (rowl == 0) feat_out[(size_t)(t0b + r) * 128 + col] = f2b(v);
        float pl = v * alv;
        float pr = v * arv;
#pragma unroll
        for (int msk = 1; msk < 16; msk <<= 1) {
          pl += __shfl_xor(pl, msk, 64);
          pr += __shfl_xor(pr, msk, 64);
        }
        if (r16 == 0 && rowl == 0) {
          elr_out[(t0b + r) * 16 + f] = pl;
          elr_out[(t0b + r) * 16 + 8 + f] = pr;
        }
      }
    }
  }
}

// ---------------- last layer: fused agg (1 node/wave, 16 waves) + in-block GEMM ----------------
#define GT_STRIDE 1032
__global__ __launch_bounds__(1024) void agg_gemm16(
    const int* __restrict__ off, const int* __restrict__ csr_src,
    const unsigned short* __restrict__ hb, const float* __restrict__ elr,
    const unsigned short* __restrict__ wpsz, const float* __restrict__ hres,
    const float* __restrict__ mb, float* __restrict__ out) {
  __shared__ __align__(16) unsigned short gt[16][GT_STRIDE];
  __shared__ float red[8][64][4];
  __shared__ float a_lds[16][64];
  __shared__ int s_lds[16][8];
  __shared__ float zi_lds[16][8];
  const int wid = threadIdx.x >> 6;
  const int lane = threadIdx.x & 63;
  const int t0 = blockIdx.x * 16;
  const int t = t0 + wid;
  const int e_loc = lane >> 3, hh = lane & 7;

  // ---- phase 1: aggregate node t (1 node/wave) ----
  {
    const int beg = off[t], end = off[t + 1];
    const float ert = elr[t * 16 + 8 + hh];
    int e = beg + e_loc;
    bool val = e < end;
    int s = val ? csr_src[e] : 0;
    float xl = val ? elr[s * 16 + hh] : 0.f;

    float z = 0.f;
    float accA[8], accB[8];
#pragma unroll
    for (int k = 0; k < 8; ++k) accA[k] = accB[k] = 0.f;

    for (int base = beg; base < end; base += 8) {
      float ex = 0.f;
      if (val) {
        float xv = xl + ert;
        xv = xv > 0.f ? xv : 0.2f * xv;
        ex = __expf(xv);
      }
      a_lds[wid][lane] = ex;
      if (hh == 0) s_lds[wid][e_loc] = s;
      __builtin_amdgcn_wave_barrier();
      asm volatile("s_waitcnt lgkmcnt(0)" ::: "memory");
      z += ex;
      int en = base + 8 + e_loc;
      bool valn = en < end;
      int sn = valn ? csr_src[en] : 0;
      float xln = valn ? elr[sn * 16 + hh] : 0.f;
      int n = min(8, end - base);
      if (n == 8) {
#pragma unroll
        for (int e2 = 0; e2 < 8; ++e2) {
          int s2 = s_lds[wid][e2];
          float4 pa = *(const float4*)&a_lds[wid][e2 * 8];
          float4 pb = *(const float4*)&a_lds[wid][e2 * 8 + 4];
          unsigned int hv = *(const unsigned int*)&hb[(size_t)s2 * 128 + 2 * lane];
          float h0 = b2f((unsigned short)(hv & 0xffffu));
          float h1 = b2f((unsigned short)(hv >> 16));
          accA[0] += pa.x * h0; accB[0] += pa.x * h1;
          accA[1] += pa.y * h0; accB[1] += pa.y * h1;
          accA[2] += pa.z * h0; accB[2] += pa.z * h1;
          accA[3] += pa.w * h0; accB[3] += pa.w * h1;
          accA[4] += pb.x * h0; accB[4] += pb.x * h1;
          accA[5] += pb.y * h0; accB[5] += pb.y * h1;
          accA[6] += pb.z * h0; accB[6] += pb.z * h1;
          accA[7] += pb.w * h0; accB[7] += pb.w * h1;
        }
      } else {
        for (int e2 = 0; e2 < n; ++e2) {
          int s2 = s_lds[wid][e2];
          float4 pa = *(const float4*)&a_lds[wid][e2 * 8];
          float4 pb = *(const float4*)&a_lds[wid][e2 * 8 + 4];
          unsigned int hv = *(const unsigned int*)&hb[(size_t)s2 * 128 + 2 * lane];
          float h0 = b2f((unsigned short)(hv & 0xffffu));
          float h1 = b2f((unsigned short)(hv >> 16));
          accA[0] += pa.x * h0; accB[0] += pa.x * h1;
          accA[1] += pa.y * h0; accB[1] += pa.y * h1;
          accA[2] += pa.z * h0; accB[2] += pa.z * h1;
          accA[3] += pa.w * h0; accB[3] += pa.w * h1;
          accA[4] += pb.x * h0; accB[4] += pb.x * h1;
          accA[5] += pb.y * h0; accB[5] += pb.y * h1;
          accA[6] += pb.z * h0; accB[6] += pb.z * h1;
          accA[7] += pb.w * h0; accB[7] += pb.w * h1;
        }
      }
      __builtin_amdgcn_wave_barrier();
      s = sn;
      xl = xln;
      val = valn;
    }
    z += __shfl_xor(z, 8, 64);
    z += __shfl_xor(z, 16, 64);
    z += __shfl_xor(z, 32, 64);
    if (e_loc == 0) zi_lds[wid][hh] = (z > 0.f) ? 1.f / z : 0.f;
    __builtin_amdgcn_wave_barrier();
    asm volatile("s_waitcnt lgkmcnt(0)" ::: "memory");
    float4 zia = *(const float4*)&zi_lds[wid][0];
    float4 zib = *(const float4*)&zi_lds[wid][4];
    float ziv[8] = {zia.x, zia.y, zia.z, zia.w, zib.x, zib.y, zib.z, zib.w};
#pragma unroll
    for (int h2 = 0; h2 < 8; ++h2) {
      *(ushort2*)&gt[wid][h2 * 128 + 2 * lane] =
          make_ushort2(f2b(accA[h2] * ziv[h2]), f2b(accB[h2] * ziv[h2]));
    }
  }
  __syncthreads();

  // ---- phase 2: out[16,128] = gt @ wpsz + hres + mb ----
  const int f = wid & 7;    // fragment col block (16 cols)
  const int kh = wid >> 3;  // K half
  const int ar16 = lane & 15;
  const int kg = lane >> 4;
  f32x4 acc = {0.f, 0.f, 0.f, 0.f};
#pragma unroll 4
  for (int ksl = 0; ksl < 16; ++ksl) {
    int ks = kh * 16 + ksl;
    bf16x8 a = *(const bf16x8*)&gt[ar16][ks * 32 + kg * 8];
    bf16x8 b = *(const bf16x8*)(wpsz + (((size_t)(ks * 8 + f) * 64 + lane) << 3));
    acc = __builtin_amdgcn_mfma_f32_16x16x32_bf16(a, b, acc, 0, 0, 0);
  }
  if (kh == 1) {
    *(float4*)&red[f][lane][0] = make_float4(acc[0], acc[1], acc[2], acc[3]);
  }
  __syncthreads();
  if (kh == 0) {
    float4 p = *(const float4*)&red[f][lane][0];
    const int col = f * 16 + (lane & 15);
    const int rb = (lane >> 4) * 4;
    float r4[4] = {p.x, p.y, p.z, p.w};
#pragma unroll
    for (int r = 0; r < 4; ++r) {
      int row = t0 + rb + r;
      out[(size_t)row * 128 + col] =
          acc[r] + r4[r] + hres[(size_t)row * 128 + col] + mb[col];
    }
  }
}

extern "C" void kernel_launch(void* const* d_in, const int* in_sizes, int n_in,
                              void* d_out, int out_size, void* d_ws, size_t ws_size,
                              hipStream_t stream) {
  const float* x = (const float*)d_in[0];
  const int* src = (const int*)d_in[1];
  const int* dst = (const int*)d_in[2];
  const float* Ws = (const float*)d_in[3];
  const float* als = (const float*)d_in[4];
  const float* ars = (const float*)d_in[5];
  const float* bs = (const float*)d_in[6];
  const float* W_last = (const float*)d_in[7];
  const float* al_last = (const float*)d_in[8];
  const float* ar_last = (const float*)d_in[9];
  const float* b_last = (const float*)d_in[10];
  float* out = (float*)d_out;

  // ---- workspace layout ----
  float* h = (float*)d_ws;                           // 2,560,000 f
  float* elr0 = h + 2560000;                         // 320,000 f (layer-0 scores)
  float* elrB = elr0 + 320000;                       // 320,000 f (layer-1 scores)
  float* elr2 = elrB + 320000;                       // 320,000 f (last-layer scores)
  float* mb = elr2 + 320000;                         // 128 f
  unsigned short* hb = (unsigned short*)(mb + 128);  // 2,560,000 us
  unsigned short* featA = hb + 2560000;              // 2,560,000 us
  unsigned short* featB = featA + 2560000;           // 2,560,000 us
  unsigned short* wsz = featB + 2560000;             // 32,768 us
  unsigned short* wpsz = wsz + 32768;                // 131,072 us
  unsigned short* wlrsz = wpsz + 131072;             // 2,048 us
  int* deg = (int*)(wlrsz + 2048);                   // N
  int* off = deg + N_NODES;                          // N+1
  int* rank = off + N_NODES + 1;                     // E
  int* csr_src = rank + N_EDGES;                     // E

  const int GB = N_NODES / 32;            // 625
  const int FB = N_NODES / 4;             // 5000
  const int EB = (N_EDGES + 255) / 256;   // 782

  degzero<<<(N_NODES + 255) / 256, 256, 0, stream>>>(deg);
  prep_all<<<(N_NODES * DM / 4 + 255) / 256, 256, 0, stream>>>(
      x, h, hb, dst, deg, rank, Ws, wsz, W_last, wpsz, al_last, ar_last, b_last, wlrsz, mb);
  scan_deg<<<1, 1024, 0, stream>>>(deg, off);
  gemm0_scatter<<<GB + EB, 256, 0, stream>>>(hb, wsz, featA, als, ars, elr0, src, dst,
                                             rank, off, csr_src);
  // layer 0 agg + fused layer-1 GEMM/scores (separate out buffers featB/elrB: race-free)
  fused_small<0><<<FB, 256, 0, stream>>>(off, csr_src, featA, elr0, bs, h, hb,
                                         wsz + 16384, als + 128, ars + 128, featB, elrB,
                                         nullptr, nullptr);
  // layer 1 agg + fused elr_last epilogue
  fused_small<1><<<FB, 256, 0, stream>>>(off, csr_src, featB, elrB, bs + 128, h, hb,
                                         nullptr, nullptr, nullptr, nullptr, nullptr,
                                         wlrsz, elr2);
  agg_gemm16<<<N_NODES / 16, 1024, 0, stream>>>(off, csr_src, hb, elr2, wpsz, h, mb, out);
}